// Round 1
// 363.738 us; speedup vs baseline: 1.0998x; 1.0998x over previous
//
#include <hip/hip_runtime.h>

typedef unsigned short u16;
typedef unsigned int   u32;
typedef _Float16 f16;
typedef _Float16 h2  __attribute__((ext_vector_type(2)));
typedef _Float16 h8  __attribute__((ext_vector_type(8)));
typedef float    fx4 __attribute__((ext_vector_type(4)));

// ---- problem constants ----
// B=4 L=6 X=Y=8 -> 256 sites, W=49 window, D=256, h=8, dh=32
#define SCALE_Q 0.17677669529663687f

__device__ __forceinline__ u16 f2h_bits(float f){
  union{ f16 h; u16 u; } v; v.h = (f16)f; return v.u;
}
__device__ __forceinline__ u32 packh2(float a, float b){
  union{ h2 h; u32 u; } v; v.h = h2{(f16)a, (f16)b}; return v.u;
}
__device__ __forceinline__ h2 as_h2(u32 x){
  union{ u32 u; h2 h; } v; v.u = x; return v.h;
}

// diagnostic fill (fp32): encodes which runtime assumption failed
__global__ void flag_fill(float* out, int n, float v){
  int i = blockIdx.x*256 + threadIdx.x;
  if (i < n) out[i] = v;
}

// ---------------------------------------------------------------------------
// K0: fuse relation matrices into projection weights (fp32 in, f16 out).
// NEW LAYOUT: k-step-major  Wft[rel][k/32][n][k&31]  so that a wave's MFMA
// B-fragment load (16 n-rows x 32 k) is one CONTIGUOUS 1KB burst.
// ---------------------------------------------------------------------------
__global__ __launch_bounds__(512) void fuse_w(
    const float* __restrict__ Wk, const float* __restrict__ Wv,
    const float* __restrict__ Ratt, const float* __restrict__ Rmsg,
    u16* __restrict__ Wft)
{
  const int rel = blockIdx.x;      // 0..3
  const int d   = blockIdx.y;      // 0..255  (k index)
  const int n   = threadIdx.x;     // 0..511
  const int ml  = rel & 1;
  float acc = 0.f;
  if (n < 256) {
    const int h = n >> 5, p = n & 31;
    const float* wcol = Wk + (size_t)ml*65536 + (size_t)(h*32)*256 + d;
    const float* rrow = Ratt + ((size_t)(rel*8 + h)*32 + p)*32;
    #pragma unroll
    for (int q = 0; q < 32; ++q) acc += wcol[q*256] * rrow[q];
  } else {
    const int n2 = n - 256, h = n2 >> 5, qq = n2 & 31;
    const float* wcol = Wv + (size_t)ml*65536 + (size_t)(h*32)*256 + d;
    const float* rcol = Rmsg + ((size_t)(rel*8 + h)*32)*32 + qq;
    #pragma unroll
    for (int p2 = 0; p2 < 32; ++p2) acc += wcol[p2*256] * rcol[p2*32];
  }
  // [rel][d>>5][n][d&31]
  Wft[(size_t)rel*131072 + (size_t)(d >> 5)*16384 + (size_t)n*32 + (d & 31)] = f2h_bits(acc);
}

__global__ __launch_bounds__(512) void fuse_b(
    const float* __restrict__ bk, const float* __restrict__ bv,
    const float* __restrict__ Ratt, const float* __restrict__ Rmsg,
    float* __restrict__ bff)
{
  const int rel = blockIdx.x, n = threadIdx.x, ml = rel & 1;
  float acc = 0.f;
  if (n < 256) {
    const int h = n >> 5, p = n & 31;
    const float* rrow = Ratt + ((size_t)(rel*8 + h)*32 + p)*32;
    #pragma unroll
    for (int q = 0; q < 32; ++q) acc += bk[ml*256 + h*32 + q] * rrow[q];
  } else {
    const int n2 = n - 256, h = n2 >> 5, qq = n2 & 31;
    const float* rcol = Rmsg + ((size_t)(rel*8 + h)*32)*32 + qq;
    #pragma unroll
    for (int p2 = 0; p2 < 32; ++p2) acc += bv[ml*256 + h*32 + p2] * rcol[p2*32];
  }
  bff[rel*512 + n] = acc;
}

// ---------------------------------------------------------------------------
// K1 v5: fused kw / v_msg projection GEMM — MFMA (16x16x32 f16).
// BM=32, BN=512, grid = nb*588 (x fetched from HBM exactly once).
// Changes vs v4 (which sat at 6% MfmaUtil, latency-bound):
//  * B fragment loads are contiguous 1KB/wave bursts (k-step-major Wft).
//  * Explicit 2-stage register pipeline: 8 B-frags + 2 A-frags of step s+1
//    issued while step s's 16 MFMAs run (10 loads in flight vs ~2).
//  * First k-step's B loads issued BEFORE the A-stage barrier (their L2
//    latency hides under the HBM stage).
// Epilogue unchanged (LDS transpose, both outputs one layout (f16):
// kw/vm[bloc][xy][h][l][ef][p]).
// ---------------------------------------------------------------------------
#define ASTRIDE 264   // u16 elements per LDS row (16B-aligned, conflict-light)

__global__ __launch_bounds__(256) void gemm_kwv(
    const float* __restrict__ x, const int* __restrict__ mode,
    const u16* __restrict__ Wft, const float* __restrict__ bff,
    u16* __restrict__ kw, u16* __restrict__ vm, int b0)
{
  __shared__ u16 Smem[32*ASTRIDE];   // 16.9 KB: A-tile, then epilogue buffer
  const int rowT  = blockIdx.x;              // bloc*588 + l*98 + tile
  const int bloc = rowT / 588;
  const int rem  = rowT % 588;
  const int l = rem / 98, tile = rem % 98;
  const int b = b0 + bloc;
  const int rel = mode[b*6]*2 + mode[b*6 + l];
  const float* Abase = x + ((size_t)(b*6 + l)*3136 + (size_t)tile*32)*256;
  const int tid  = threadIdx.x;
  const int wave = tid >> 6, lane = tid & 63;
  const int quad = lane >> 4, l15 = lane & 15;

  // per-lane B base in k-step-major layout [rel][s][n][32]
  const u16* Bp = Wft + (size_t)rel*131072 + (size_t)((wave << 7) + l15)*32 + (quad << 3);

  // ---- issue k-step 0's B loads early (independent of LDS stage) ----
  h8 bcur[8];
  #pragma unroll
  for (int j = 0; j < 8; ++j) bcur[j] = *(const h8*)(Bp + j*512);

  // ---- stage A once: thread t loads row t>>3, cols (t&7)*32..+31 ----
  {
    const int r = tid >> 3, cseg = (tid & 7)*32;
    const float* src = Abase + (size_t)r*256 + cseg;
    u16* dst = &Smem[r*ASTRIDE + cseg];
    #pragma unroll
    for (int i = 0; i < 4; ++i){
      float4 f0 = *(const float4*)(src + i*8);
      float4 f1 = *(const float4*)(src + i*8 + 4);
      uint4 pk;
      pk.x = packh2(f0.x, f0.y); pk.y = packh2(f0.z, f0.w);
      pk.z = packh2(f1.x, f1.y); pk.w = packh2(f1.z, f1.w);
      *(uint4*)(dst + i*8) = pk;
    }
  }
  __syncthreads();

  fx4 acc[2][8];
  #pragma unroll
  for (int mt = 0; mt < 2; ++mt)
    #pragma unroll
    for (int j = 0; j < 8; ++j) acc[mt][j] = fx4{0,0,0,0};

  const u16* As0 = &Smem[l15*ASTRIDE + (quad << 3)];
  const u16* As1 = As0 + 16*ASTRIDE;
  h8 acur[2];
  acur[0] = *(const h8*)As0;
  acur[1] = *(const h8*)As1;

  // wave owns n-columns [wave*128, wave*128+128): 8 n-tiles x 2 m-tiles.
  // 2-stage software pipeline over the 8 k-steps.
  #pragma unroll
  for (int s = 0; s < 8; ++s) {
    h8 bnxt[8], anxt[2];
    if (s < 7) {
      const u16* bp = Bp + (size_t)(s + 1)*16384;
      #pragma unroll
      for (int j = 0; j < 8; ++j) bnxt[j] = *(const h8*)(bp + j*512);
      anxt[0] = *(const h8*)(As0 + (s + 1)*32);
      anxt[1] = *(const h8*)(As1 + (s + 1)*32);
    }
    #pragma unroll
    for (int j = 0; j < 8; ++j) {
      acc[0][j] = __builtin_amdgcn_mfma_f32_16x16x32_f16(acur[0], bcur[j], acc[0][j], 0, 0, 0);
      acc[1][j] = __builtin_amdgcn_mfma_f32_16x16x32_f16(acur[1], bcur[j], acc[1][j], 0, 0, 0);
    }
    if (s < 7) {
      #pragma unroll
      for (int j = 0; j < 8; ++j) bcur[j] = bnxt[j];
      acur[0] = anxt[0]; acur[1] = anxt[1];
    }
  }

  // ---- epilogue: LDS transpose, two halves (kw = waves 0,1 / vm = 2,3) ----
  const int row_ = tid >> 3;        // 0..31
  const int hsel = tid & 7;         // 0..7
  const int r_g  = tile*32 + row_;  // 0..3135
  const int xy   = r_g / 49, ef = r_g - xy*49;

  #pragma unroll
  for (int half = 0; half < 2; ++half){
    __syncthreads();   // protect Smem (A-tile reads / previous half's reads)
    if ((wave >> 1) == half){
      #pragma unroll
      for (int j = 0; j < 8; ++j){
        const int n   = wave*128 + j*16 + l15;
        const int col = n & 255;
        const float bias = bff[rel*512 + n];
        #pragma unroll
        for (int mt = 0; mt < 2; ++mt){
          #pragma unroll
          for (int reg = 0; reg < 4; ++reg){
            const int row = mt*16 + quad*4 + reg;
            Smem[row*ASTRIDE + col] = f2h_bits(acc[mt][j][reg] + bias);
          }
        }
      }
    }
    __syncthreads();
    u16* dbuf = half ? vm : kw;
    u16* dst  = dbuf + ((((size_t)(bloc*64 + xy)*8 + hsel)*6 + l)*49 + ef)*32;
    const u16* srcl = &Smem[row_*ASTRIDE + hsel*32];
    uint4 v0 = *(const uint4*)(srcl);
    uint4 v1 = *(const uint4*)(srcl + 8);
    uint4 v2 = *(const uint4*)(srcl + 16);
    uint4 v3 = *(const uint4*)(srcl + 24);
    *(uint4*)(dst)      = v0;
    *(uint4*)(dst + 8)  = v1;
    *(uint4*)(dst + 16) = v2;
    *(uint4*)(dst + 24) = v3;
  }
}

// ---------------------------------------------------------------------------
// K2: q projection (l=0 only), VALU 4x4, f16 output.
// ---------------------------------------------------------------------------
__global__ __launch_bounds__(256) void gemm_q(
    const float* __restrict__ x, const int* __restrict__ mode,
    const float* __restrict__ Wq, const float* __restrict__ bq,
    u16* __restrict__ qbuf)
{
  __shared__ float As[16][68];
  __shared__ float Bs[16][68];
  const int nbase = blockIdx.x * 64;      // 0..192
  const int rowT  = blockIdx.y;           // 0..195
  const int b = rowT / 49, tile = rowT % 49;
  const int m0 = mode[b*6];
  const float* Abase = x + ((size_t)b*6*3136 + (size_t)tile*64)*256;
  const float* Wbase = Wq + (size_t)m0*65536;
  const int tid = threadIdx.x;
  const int tx = tid & 15, ty = tid >> 4;
  const int arow = tid >> 2, acol = (tid & 3)*4;
  const int bn = tid >> 2,  bk4 = (tid & 3)*4;
  float acc[4][4] = {};
  for (int k0 = 0; k0 < 256; k0 += 16) {
    float4 ar = *(const float4*)(Abase + (size_t)arow*256 + k0 + acol);
    float4 br = *(const float4*)(Wbase + (size_t)(nbase + bn)*256 + k0 + bk4);
    __syncthreads();
    As[acol+0][arow]=ar.x; As[acol+1][arow]=ar.y; As[acol+2][arow]=ar.z; As[acol+3][arow]=ar.w;
    Bs[bk4+0][bn]=br.x; Bs[bk4+1][bn]=br.y; Bs[bk4+2][bn]=br.z; Bs[bk4+3][bn]=br.w;
    __syncthreads();
    #pragma unroll
    for (int kk = 0; kk < 16; ++kk){
      float4 a4 = *(const float4*)&As[kk][ty*4];
      float4 b4 = *(const float4*)&Bs[kk][tx*4];
      float ar_[4] = {a4.x,a4.y,a4.z,a4.w};
      float br_[4] = {b4.x,b4.y,b4.z,b4.w};
      #pragma unroll
      for (int i = 0; i < 4; ++i)
        #pragma unroll
        for (int j = 0; j < 4; ++j) acc[i][j] += ar_[i]*br_[j];
    }
  }
  const int colBase = nbase + tx*4;
  const int h = colBase >> 5, p = colBase & 31;
  float bias[4];
  #pragma unroll
  for (int j = 0; j < 4; ++j) bias[j] = bq[m0*256 + colBase + j];
  #pragma unroll
  for (int i = 0; i < 4; ++i){
    int r = tile*64 + ty*4 + i;
    int xy = r / 49, ef = r - xy*49;
    size_t dst = (((size_t)(b*64 + xy)*8 + h)*49 + ef)*32 + p;
    ushort4 pk;
    pk.x = f2h_bits((acc[i][0]+bias[0])*SCALE_Q);
    pk.y = f2h_bits((acc[i][1]+bias[1])*SCALE_Q);
    pk.z = f2h_bits((acc[i][2]+bias[2])*SCALE_Q);
    pk.w = f2h_bits((acc[i][3]+bias[3])*SCALE_Q);
    *(ushort4*)(qbuf + dst) = pk;
  }
}

// ---------------------------------------------------------------------------
// K3: attention — ONE WAVE per (bloc,xy,h); lane = query row qi (49 active).
// Scores S[49], online-softmax state, O[32] all in REGISTERS.
// K_z staged contiguously; V_z staged contiguously from the SAME [ef][p]
// layout and transposed into VT16[p][56] via u16 LDS writes (ef=49 pad
// zeroed once — uninitialized LDS could hold f16-Inf -> 0*Inf=NaN).
// QK^T and PV via v_dot2_f32_f16.   v5: K/V staging loads vectorized (uint4).
// ---------------------------------------------------------------------------
__global__ __launch_bounds__(64) void attn_kernel(
    const u16* __restrict__ qbuf, const u16* __restrict__ kw,
    const u16* __restrict__ vm,   const float* __restrict__ post,
    u16* __restrict__ aout, int b0)
{
  __shared__ float biasT[49*52];             // [ke][qi] — lane-linear reads
  __shared__ alignas(16) u32 Ks[784];        // K_z  flat [ef*16 + pp]
  __shared__ u16 VT16[32*56];                // V^T_z [p][56] (49 used, rest pad)
  __shared__ float poss[169];

  const int bloc  = blockIdx.x >> 9;
  const int local = blockIdx.x & 511;      // xy*8+h
  const int h = local & 7, xy = local >> 3;
  const int bxy = (b0 + bloc)*64 + xy;
  const int tid = threadIdx.x;             // 0..63
  const int qi = min(tid, 48);             // lane's query row (clamped)

  for (int i = tid; i < 169; i += 64) poss[i] = post[i*8 + h];
  if (tid < 32) VT16[tid*56 + 49] = 0;     // zero the ef=49 pad slot (once)
  __syncthreads();

  if (tid < 49){
    const int qa = qi/7, qb = qi - qa*7;
    for (int ka = 0; ka < 7; ++ka)
      for (int kb = 0; kb < 7; ++kb)
        biasT[(ka*7+kb)*52 + qi] = poss[(qa - ka + 6)*13 + (qb - kb + 6)];
  }

  // Q row into registers (16 u32 = 32 f16)
  u32 Qw[16];
  { const uint4* qsrc = (const uint4*)(qbuf + (size_t)(bxy*8 + h)*1568 + (size_t)qi*32);
    uint4 t0 = qsrc[0], t1 = qsrc[1], t2 = qsrc[2], t3 = qsrc[3];
    Qw[0]=t0.x; Qw[1]=t0.y; Qw[2]=t0.z; Qw[3]=t0.w;
    Qw[4]=t1.x; Qw[5]=t1.y; Qw[6]=t1.z; Qw[7]=t1.w;
    Qw[8]=t2.x; Qw[9]=t2.y; Qw[10]=t2.z; Qw[11]=t2.w;
    Qw[12]=t3.x; Qw[13]=t3.y; Qw[14]=t3.z; Qw[15]=t3.w; }

  const size_t kvbase = ((size_t)(bloc*64 + xy)*8 + h)*6;
  float mprev = -1e30f, lsum = 0.f;
  float O[32];
  #pragma unroll
  for (int p = 0; p < 32; ++p) O[p] = 0.f;

  for (int z = 0; z < 6; ++z){
    __syncthreads();   // prior phase's LDS reads complete (also covers biasT build)
    { const uint4* ksrc = (const uint4*)((const u32*)(kw) + (kvbase + z)*784);
      for (int i = tid; i < 196; i += 64) ((uint4*)Ks)[i] = ksrc[i];
      const uint4* vsrc = (const uint4*)((const u32*)(vm) + (kvbase + z)*784);
      for (int i = tid; i < 196; i += 64){
        uint4 v4 = vsrc[i];
        const int ef = i >> 2, ppb = (i & 3)*8;   // 8 halfword-rows per uint4
        VT16[(ppb+0)*56 + ef] = (u16)(v4.x & 0xFFFFu);
        VT16[(ppb+1)*56 + ef] = (u16)(v4.x >> 16);
        VT16[(ppb+2)*56 + ef] = (u16)(v4.y & 0xFFFFu);
        VT16[(ppb+3)*56 + ef] = (u16)(v4.y >> 16);
        VT16[(ppb+4)*56 + ef] = (u16)(v4.z & 0xFFFFu);
        VT16[(ppb+5)*56 + ef] = (u16)(v4.z >> 16);
        VT16[(ppb+6)*56 + ef] = (u16)(v4.w & 0xFFFFu);
        VT16[(ppb+7)*56 + ef] = (u16)(v4.w >> 16);
      } }
    __syncthreads();

    // ---- S[ke] = q . k_z + bias ----
    float S[49];
    #pragma unroll
    for (int ke = 0; ke < 49; ++ke){
      float s = biasT[ke*52 + qi];
      #pragma unroll
      for (int q4 = 0; q4 < 4; ++q4){
        uint4 k4 = *(const uint4*)&Ks[ke*16 + q4*4];
        s = __builtin_amdgcn_fdot2(as_h2(Qw[q4*4+0]), as_h2(k4.x), s, false);
        s = __builtin_amdgcn_fdot2(as_h2(Qw[q4*4+1]), as_h2(k4.y), s, false);
        s = __builtin_amdgcn_fdot2(as_h2(Qw[q4*4+2]), as_h2(k4.z), s, false);
        s = __builtin_amdgcn_fdot2(as_h2(Qw[q4*4+3]), as_h2(k4.w), s, false);
      }
      S[ke] = s;
    }

    // ---- online softmax (lane-local) ----
    float mx = mprev;
    #pragma unroll
    for (int ke = 0; ke < 49; ++ke) mx = fmaxf(mx, S[ke]);
    const float alpha = __expf(mprev - mx);
    float sum = 0.f;
    #pragma unroll
    for (int ke = 0; ke < 49; ++ke){ float e = __expf(S[ke]-mx); S[ke] = e; sum += e; }
    lsum = lsum*alpha + sum;
    mprev = mx;
    #pragma unroll
    for (int p = 0; p < 32; ++p) O[p] *= alpha;

    // ---- pack P to f16 pairs ----
    u32 Pp[25];
    #pragma unroll
    for (int kp = 0; kp < 24; ++kp) Pp[kp] = packh2(S[2*kp], S[2*kp+1]);
    Pp[24] = packh2(S[48], 0.f);

    // ---- O += P . V_z  (broadcast reads of VT16 as u32 pairs) ----
    const u32* VTs = (const u32*)VT16;   // index p*28 + rm
    #pragma unroll
    for (int p = 0; p < 32; ++p){
      float o = O[p];
      #pragma unroll
      for (int c = 0; c < 6; ++c){
        uint4 v4 = *(const uint4*)&VTs[p*28 + c*4];
        o = __builtin_amdgcn_fdot2(as_h2(Pp[c*4+0]), as_h2(v4.x), o, false);
        o = __builtin_amdgcn_fdot2(as_h2(Pp[c*4+1]), as_h2(v4.y), o, false);
        o = __builtin_amdgcn_fdot2(as_h2(Pp[c*4+2]), as_h2(v4.z), o, false);
        o = __builtin_amdgcn_fdot2(as_h2(Pp[c*4+3]), as_h2(v4.w), o, false);
      }
      o = __builtin_amdgcn_fdot2(as_h2(Pp[24]), as_h2(VTs[p*28 + 24]), o, false);
      O[p] = o;
    }
  }

  // ---- normalize + store (f16) ----
  if (tid < 49){
    const float inv = 1.f / lsum;
    u32* outw = (u32*)(aout + (size_t)bxy*12544 + h*32);
    #pragma unroll
    for (int pp = 0; pp < 16; ++pp)
      outw[(size_t)qi*128 + pp] = packh2(O[2*pp]*inv, O[2*pp+1]*inv);
  }
}

// ---------------------------------------------------------------------------
// K4: final projection. A = attn out (f16), B = Wa[m0] fp32 [e][d], bias ba.
// ---------------------------------------------------------------------------
__global__ __launch_bounds__(256) void gemm_out(
    const u16* __restrict__ aout, const int* __restrict__ mode,
    const float* __restrict__ Wa, const float* __restrict__ ba,
    float* __restrict__ outp)
{
  __shared__ float As[16][68];
  __shared__ float Bs[16][68];
  const int nbase = blockIdx.x * 64;
  const int rowT  = blockIdx.y;           // 0..195
  const int b = rowT / 49, tile = rowT % 49;
  const int m0 = mode[b*6];
  const u16* Abase = aout + ((size_t)b*3136 + (size_t)tile*64)*256;
  const float* Wbase = Wa + (size_t)m0*65536;
  const int tid = threadIdx.x;
  const int tx = tid & 15, ty = tid >> 4;
  const int arow = tid >> 2, acol = (tid & 3)*4;
  const int bn = tid >> 2,  bk4 = (tid & 3)*4;
  float acc[4][4] = {};
  for (int k0 = 0; k0 < 256; k0 += 16) {
    uint2  ar = *(const uint2*)(Abase + (size_t)arow*256 + k0 + acol);
    float4 br = *(const float4*)(Wbase + (size_t)(nbase + bn)*256 + k0 + bk4);
    __syncthreads();
    { h2 lo = as_h2(ar.x), hi = as_h2(ar.y);
      As[acol+0][arow]=(float)lo.x; As[acol+1][arow]=(float)lo.y;
      As[acol+2][arow]=(float)hi.x; As[acol+3][arow]=(float)hi.y; }
    Bs[bk4+0][bn]=br.x; Bs[bk4+1][bn]=br.y; Bs[bk4+2][bn]=br.z; Bs[bk4+3][bn]=br.w;
    __syncthreads();
    #pragma unroll
    for (int kk = 0; kk < 16; ++kk){
      float4 a4 = *(const float4*)&As[kk][ty*4];
      float4 b4 = *(const float4*)&Bs[kk][tx*4];
      float ar_[4] = {a4.x,a4.y,a4.z,a4.w};
      float br_[4] = {b4.x,b4.y,b4.z,b4.w};
      #pragma unroll
      for (int i = 0; i < 4; ++i)
        #pragma unroll
        for (int j = 0; j < 4; ++j) acc[i][j] += ar_[i]*br_[j];
    }
  }
  const int colBase = nbase + tx*4;
  float bias[4];
  #pragma unroll
  for (int j = 0; j < 4; ++j) bias[j] = ba[m0*256 + colBase + j];
  #pragma unroll
  for (int i = 0; i < 4; ++i){
    int rowg = b*3136 + tile*64 + ty*4 + i;
    float4 o;
    o.x = acc[i][0] + bias[0];
    o.y = acc[i][1] + bias[1];
    o.z = acc[i][2] + bias[2];
    o.w = acc[i][3] + bias[3];
    *(float4*)(outp + (size_t)rowg*256 + colBase) = o;
  }
}

// ---------------------------------------------------------------------------
extern "C" void kernel_launch(void* const* d_in, const int* in_sizes, int n_in,
                              void* d_out, int out_size, void* d_ws, size_t ws_size,
                              hipStream_t stream)
{
  float* outp = (float*)d_out;
  const int FLAG_GRID = (out_size + 255)/256;

  if (n_in != 13) { flag_fill<<<FLAG_GRID,256,0,stream>>>(outp, out_size, 2000.f); return; }
  if (in_sizes[0] != 4*6*64*49*256) { flag_fill<<<FLAG_GRID,256,0,stream>>>(outp, out_size, 3000.f); return; }
  if (in_sizes[1] != 24) { flag_fill<<<FLAG_GRID,256,0,stream>>>(outp, out_size, 4000.f); return; }

  const size_t SZ_WFT  = (size_t)4*512*256*2;               //  1 MB (f16)
  const size_t SZ_BFF  = (size_t)4*512*sizeof(float);       //  8 KB
  const size_t SZ_Q    = (size_t)12544*256*2;               //  6.4 MB (f16)
  const size_t SZ_AOUT = (size_t)12544*256*2;               //  6.4 MB (f16)
  const size_t SZ_KW1  = (size_t)64*8*6*49*32*2;            //  9.63 MB / batch
  const size_t SZ_VM1  = SZ_KW1;                            //  unified layout
  const size_t FIXED   = SZ_WFT + SZ_BFF + SZ_Q + SZ_AOUT;
  if (ws_size < FIXED + SZ_KW1 + SZ_VM1) { flag_fill<<<FLAG_GRID,256,0,stream>>>(outp, out_size, 1000.f); return; }

  int nb = 1;
  if (ws_size >= FIXED + 4*(SZ_KW1 + SZ_VM1)) nb = 4;
  else if (ws_size >= FIXED + 2*(SZ_KW1 + SZ_VM1)) nb = 2;

  const float* x    = (const float*)d_in[0];
  const int*   mode = (const int*)d_in[1];
  const float* Wq   = (const float*)d_in[2];
  const float* bq   = (const float*)d_in[3];
  const float* Wk   = (const float*)d_in[4];
  const float* bk   = (const float*)d_in[5];
  const float* Wv   = (const float*)d_in[6];
  const float* bv   = (const float*)d_in[7];
  const float* Wa   = (const float*)d_in[8];
  const float* ba   = (const float*)d_in[9];
  const float* Ratt = (const float*)d_in[10];
  const float* Rmsg = (const float*)d_in[11];
  const float* post = (const float*)d_in[12];

  char* w = (char*)d_ws;
  u16* Wft   = (u16*)w;   w += SZ_WFT;
  float* bff = (float*)w; w += SZ_BFF;
  u16* qbuf  = (u16*)w;   w += SZ_Q;
  u16* aout  = (u16*)w;   w += SZ_AOUT;
  u16* kwbuf = (u16*)w;   w += (size_t)nb*SZ_KW1;
  u16* vmbuf = (u16*)w;   w += (size_t)nb*SZ_VM1;

  fuse_w<<<dim3(4,256), 512, 0, stream>>>(Wk, Wv, Ratt, Rmsg, Wft);
  fuse_b<<<4, 512, 0, stream>>>(bk, bv, Ratt, Rmsg, bff);
  gemm_q<<<dim3(4,196), 256, 0, stream>>>(x, mode, Wq, bq, qbuf);
  for (int b0 = 0; b0 < 4; b0 += nb) {
    gemm_kwv<<<nb*588, 256, 0, stream>>>(x, mode, Wft, bff, kwbuf, vmbuf, b0);
    attn_kernel<<<nb*512, 64, 0, stream>>>(qbuf, kwbuf, vmbuf, post, aout, b0);
  }
  gemm_out<<<dim3(4,196), 256, 0, stream>>>(aout, mode, Wa, ba, outp);
}

// Round 2
// 330.601 us; speedup vs baseline: 1.2101x; 1.1002x over previous
//
#include <hip/hip_runtime.h>

typedef unsigned short u16;
typedef unsigned int   u32;
typedef _Float16 f16;
typedef _Float16 h2  __attribute__((ext_vector_type(2)));
typedef _Float16 h8  __attribute__((ext_vector_type(8)));
typedef float    fx4 __attribute__((ext_vector_type(4)));

// ---- problem constants ----
// B=4 L=6 X=Y=8 -> 256 sites, W=49 window, D=256, h=8, dh=32
#define SCALE_Q 0.17677669529663687f

__device__ __forceinline__ u16 f2h_bits(float f){
  union{ f16 h; u16 u; } v; v.h = (f16)f; return v.u;
}
__device__ __forceinline__ u32 packh2(float a, float b){
  union{ h2 h; u32 u; } v; v.h = h2{(f16)a, (f16)b}; return v.u;
}
__device__ __forceinline__ h2 as_h2(u32 x){
  union{ u32 u; h2 h; } v; v.u = x; return v.h;
}

// diagnostic fill (fp32): encodes which runtime assumption failed
__global__ void flag_fill(float* out, int n, float v){
  int i = blockIdx.x*256 + threadIdx.x;
  if (i < n) out[i] = v;
}

// ---------------------------------------------------------------------------
// K0: fuse relation matrices into projection weights (fp32 in, f16 out).
// k-step-major layout  Wft[rel][k/32][n][k&31]  so that a wave's MFMA
// B-fragment load (16 n-rows x 32 k) is one CONTIGUOUS 1KB burst.
// ---------------------------------------------------------------------------
__global__ __launch_bounds__(512) void fuse_w(
    const float* __restrict__ Wk, const float* __restrict__ Wv,
    const float* __restrict__ Ratt, const float* __restrict__ Rmsg,
    u16* __restrict__ Wft)
{
  const int rel = blockIdx.x;      // 0..3
  const int d   = blockIdx.y;      // 0..255  (k index)
  const int n   = threadIdx.x;     // 0..511
  const int ml  = rel & 1;
  float acc = 0.f;
  if (n < 256) {
    const int h = n >> 5, p = n & 31;
    const float* wcol = Wk + (size_t)ml*65536 + (size_t)(h*32)*256 + d;
    const float* rrow = Ratt + ((size_t)(rel*8 + h)*32 + p)*32;
    #pragma unroll
    for (int q = 0; q < 32; ++q) acc += wcol[q*256] * rrow[q];
  } else {
    const int n2 = n - 256, h = n2 >> 5, qq = n2 & 31;
    const float* wcol = Wv + (size_t)ml*65536 + (size_t)(h*32)*256 + d;
    const float* rcol = Rmsg + ((size_t)(rel*8 + h)*32)*32 + qq;
    #pragma unroll
    for (int p2 = 0; p2 < 32; ++p2) acc += wcol[p2*256] * rcol[p2*32];
  }
  // [rel][d>>5][n][d&31]
  Wft[(size_t)rel*131072 + (size_t)(d >> 5)*16384 + (size_t)n*32 + (d & 31)] = f2h_bits(acc);
}

__global__ __launch_bounds__(512) void fuse_b(
    const float* __restrict__ bk, const float* __restrict__ bv,
    const float* __restrict__ Ratt, const float* __restrict__ Rmsg,
    float* __restrict__ bff)
{
  const int rel = blockIdx.x, n = threadIdx.x, ml = rel & 1;
  float acc = 0.f;
  if (n < 256) {
    const int h = n >> 5, p = n & 31;
    const float* rrow = Ratt + ((size_t)(rel*8 + h)*32 + p)*32;
    #pragma unroll
    for (int q = 0; q < 32; ++q) acc += bk[ml*256 + h*32 + q] * rrow[q];
  } else {
    const int n2 = n - 256, h = n2 >> 5, qq = n2 & 31;
    const float* rcol = Rmsg + ((size_t)(rel*8 + h)*32)*32 + qq;
    #pragma unroll
    for (int p2 = 0; p2 < 32; ++p2) acc += bv[ml*256 + h*32 + p2] * rcol[p2*32];
  }
  bff[rel*512 + n] = acc;
}

// ---------------------------------------------------------------------------
// K1 v5: fused kw / v_msg projection GEMM — MFMA (16x16x32 f16).
// BM=32, BN=512, grid = nb*588 (x fetched from HBM exactly once).
// B fragment loads are contiguous 1KB/wave bursts (k-step-major Wft) with an
// explicit 2-stage register pipeline; first k-step's B loads issued before
// the A-stage barrier. Epilogue via LDS transpose; both outputs share one
// f16 layout: kw/vm[bloc][xy][h][l][ef][p].
// ---------------------------------------------------------------------------
#define ASTRIDE 264   // u16 elements per LDS row (16B-aligned, conflict-light)

__global__ __launch_bounds__(256) void gemm_kwv(
    const float* __restrict__ x, const int* __restrict__ mode,
    const u16* __restrict__ Wft, const float* __restrict__ bff,
    u16* __restrict__ kw, u16* __restrict__ vm, int b0)
{
  __shared__ u16 Smem[32*ASTRIDE];   // 16.9 KB: A-tile, then epilogue buffer
  const int rowT  = blockIdx.x;              // bloc*588 + l*98 + tile
  const int bloc = rowT / 588;
  const int rem  = rowT % 588;
  const int l = rem / 98, tile = rem % 98;
  const int b = b0 + bloc;
  const int rel = mode[b*6]*2 + mode[b*6 + l];
  const float* Abase = x + ((size_t)(b*6 + l)*3136 + (size_t)tile*32)*256;
  const int tid  = threadIdx.x;
  const int wave = tid >> 6, lane = tid & 63;
  const int quad = lane >> 4, l15 = lane & 15;

  // per-lane B base in k-step-major layout [rel][s][n][32]
  const u16* Bp = Wft + (size_t)rel*131072 + (size_t)((wave << 7) + l15)*32 + (quad << 3);

  // ---- issue k-step 0's B loads early (independent of LDS stage) ----
  h8 bcur[8];
  #pragma unroll
  for (int j = 0; j < 8; ++j) bcur[j] = *(const h8*)(Bp + j*512);

  // ---- stage A once: thread t loads row t>>3, cols (t&7)*32..+31 ----
  {
    const int r = tid >> 3, cseg = (tid & 7)*32;
    const float* src = Abase + (size_t)r*256 + cseg;
    u16* dst = &Smem[r*ASTRIDE + cseg];
    #pragma unroll
    for (int i = 0; i < 4; ++i){
      float4 f0 = *(const float4*)(src + i*8);
      float4 f1 = *(const float4*)(src + i*8 + 4);
      uint4 pk;
      pk.x = packh2(f0.x, f0.y); pk.y = packh2(f0.z, f0.w);
      pk.z = packh2(f1.x, f1.y); pk.w = packh2(f1.z, f1.w);
      *(uint4*)(dst + i*8) = pk;
    }
  }
  __syncthreads();

  fx4 acc[2][8];
  #pragma unroll
  for (int mt = 0; mt < 2; ++mt)
    #pragma unroll
    for (int j = 0; j < 8; ++j) acc[mt][j] = fx4{0,0,0,0};

  const u16* As0 = &Smem[l15*ASTRIDE + (quad << 3)];
  const u16* As1 = As0 + 16*ASTRIDE;
  h8 acur[2];
  acur[0] = *(const h8*)As0;
  acur[1] = *(const h8*)As1;

  // wave owns n-columns [wave*128, wave*128+128): 8 n-tiles x 2 m-tiles.
  // 2-stage software pipeline over the 8 k-steps.
  #pragma unroll
  for (int s = 0; s < 8; ++s) {
    h8 bnxt[8], anxt[2];
    if (s < 7) {
      const u16* bp = Bp + (size_t)(s + 1)*16384;
      #pragma unroll
      for (int j = 0; j < 8; ++j) bnxt[j] = *(const h8*)(bp + j*512);
      anxt[0] = *(const h8*)(As0 + (s + 1)*32);
      anxt[1] = *(const h8*)(As1 + (s + 1)*32);
    }
    #pragma unroll
    for (int j = 0; j < 8; ++j) {
      acc[0][j] = __builtin_amdgcn_mfma_f32_16x16x32_f16(acur[0], bcur[j], acc[0][j], 0, 0, 0);
      acc[1][j] = __builtin_amdgcn_mfma_f32_16x16x32_f16(acur[1], bcur[j], acc[1][j], 0, 0, 0);
    }
    if (s < 7) {
      #pragma unroll
      for (int j = 0; j < 8; ++j) bcur[j] = bnxt[j];
      acur[0] = anxt[0]; acur[1] = anxt[1];
    }
  }

  // ---- epilogue: LDS transpose, two halves (kw = waves 0,1 / vm = 2,3) ----
  const int row_ = tid >> 3;        // 0..31
  const int hsel = tid & 7;         // 0..7
  const int r_g  = tile*32 + row_;  // 0..3135
  const int xy   = r_g / 49, ef = r_g - xy*49;

  #pragma unroll
  for (int half = 0; half < 2; ++half){
    __syncthreads();   // protect Smem (A-tile reads / previous half's reads)
    if ((wave >> 1) == half){
      #pragma unroll
      for (int j = 0; j < 8; ++j){
        const int n   = wave*128 + j*16 + l15;
        const int col = n & 255;
        const float bias = bff[rel*512 + n];
        #pragma unroll
        for (int mt = 0; mt < 2; ++mt){
          #pragma unroll
          for (int reg = 0; reg < 4; ++reg){
            const int row = mt*16 + quad*4 + reg;
            Smem[row*ASTRIDE + col] = f2h_bits(acc[mt][j][reg] + bias);
          }
        }
      }
    }
    __syncthreads();
    u16* dbuf = half ? vm : kw;
    u16* dst  = dbuf + ((((size_t)(bloc*64 + xy)*8 + hsel)*6 + l)*49 + ef)*32;
    const u16* srcl = &Smem[row_*ASTRIDE + hsel*32];
    uint4 v0 = *(const uint4*)(srcl);
    uint4 v1 = *(const uint4*)(srcl + 8);
    uint4 v2 = *(const uint4*)(srcl + 16);
    uint4 v3 = *(const uint4*)(srcl + 24);
    *(uint4*)(dst)      = v0;
    *(uint4*)(dst + 8)  = v1;
    *(uint4*)(dst + 16) = v2;
    *(uint4*)(dst + 24) = v3;
  }
}

// ---------------------------------------------------------------------------
// K2: q projection (l=0 only), VALU 4x4, f16 output.
// ---------------------------------------------------------------------------
__global__ __launch_bounds__(256) void gemm_q(
    const float* __restrict__ x, const int* __restrict__ mode,
    const float* __restrict__ Wq, const float* __restrict__ bq,
    u16* __restrict__ qbuf)
{
  __shared__ float As[16][68];
  __shared__ float Bs[16][68];
  const int nbase = blockIdx.x * 64;      // 0..192
  const int rowT  = blockIdx.y;           // 0..195
  const int b = rowT / 49, tile = rowT % 49;
  const int m0 = mode[b*6];
  const float* Abase = x + ((size_t)b*6*3136 + (size_t)tile*64)*256;
  const float* Wbase = Wq + (size_t)m0*65536;
  const int tid = threadIdx.x;
  const int tx = tid & 15, ty = tid >> 4;
  const int arow = tid >> 2, acol = (tid & 3)*4;
  const int bn = tid >> 2,  bk4 = (tid & 3)*4;
  float acc[4][4] = {};
  for (int k0 = 0; k0 < 256; k0 += 16) {
    float4 ar = *(const float4*)(Abase + (size_t)arow*256 + k0 + acol);
    float4 br = *(const float4*)(Wbase + (size_t)(nbase + bn)*256 + k0 + bk4);
    __syncthreads();
    As[acol+0][arow]=ar.x; As[acol+1][arow]=ar.y; As[acol+2][arow]=ar.z; As[acol+3][arow]=ar.w;
    Bs[bk4+0][bn]=br.x; Bs[bk4+1][bn]=br.y; Bs[bk4+2][bn]=br.z; Bs[bk4+3][bn]=br.w;
    __syncthreads();
    #pragma unroll
    for (int kk = 0; kk < 16; ++kk){
      float4 a4 = *(const float4*)&As[kk][ty*4];
      float4 b4 = *(const float4*)&Bs[kk][tx*4];
      float ar_[4] = {a4.x,a4.y,a4.z,a4.w};
      float br_[4] = {b4.x,b4.y,b4.z,b4.w};
      #pragma unroll
      for (int i = 0; i < 4; ++i)
        #pragma unroll
        for (int j = 0; j < 4; ++j) acc[i][j] += ar_[i]*br_[j];
    }
  }
  const int colBase = nbase + tx*4;
  const int h = colBase >> 5, p = colBase & 31;
  float bias[4];
  #pragma unroll
  for (int j = 0; j < 4; ++j) bias[j] = bq[m0*256 + colBase + j];
  #pragma unroll
  for (int i = 0; i < 4; ++i){
    int r = tile*64 + ty*4 + i;
    int xy = r / 49, ef = r - xy*49;
    size_t dst = (((size_t)(b*64 + xy)*8 + h)*49 + ef)*32 + p;
    ushort4 pk;
    pk.x = f2h_bits((acc[i][0]+bias[0])*SCALE_Q);
    pk.y = f2h_bits((acc[i][1]+bias[1])*SCALE_Q);
    pk.z = f2h_bits((acc[i][2]+bias[2])*SCALE_Q);
    pk.w = f2h_bits((acc[i][3]+bias[3])*SCALE_Q);
    *(ushort4*)(qbuf + dst) = pk;
  }
}

// ---------------------------------------------------------------------------
// K3 v6: attention — ONE WAVE per (bloc,xy,h), now MFMA-based.
// S^T = K·Q^T via 16x16x32_f16 (A = K rows, B = Q rows, C-in = pos-bias held
// in 64 VGPRs; ke>=49 masked with -1e30 in C-in; Q/K pad rows zeroed).
// Softmax per qi-column: column qi lives at lane&15, reduce over 4 regs x
// 4 mt-tiles in-lane + 2 shfl_xor across quads. Online m/l per column.
// P^T staged to XOR-swizzled LDS (b64 writes / conflict-free b128 reads).
// O^T += V^T·P^T via MFMA; V^T built by the staging scatter-transpose into a
// chunk-XOR-swizzled [p][ke] buffer (conflict-free b128 A-frag reads).
// Output normalized and stored via LDS roundtrip (coalesced uint4 stores).
// ---------------------------------------------------------------------------
__global__ __launch_bounds__(64) void attn_kernel(
    const u16* __restrict__ qbuf, const u16* __restrict__ kw,
    const u16* __restrict__ vm,   const float* __restrict__ post,
    u16* __restrict__ aout, int b0)
{
  __shared__ u32 Ks[64*16];     // K rows [ke][p] (ke 49..63 zeroed once)   4KB
  __shared__ u16 VT[32*64];     // V^T [p][ke], ke-chunk XOR-swizzled       4KB
  __shared__ u16 PQ[64*64];     // Q staging [qi][32] -> P^T [qi][ke] swz   8KB
  __shared__ float poss[169];

  const int bloc  = blockIdx.x >> 9;
  const int local = blockIdx.x & 511;      // xy*8+h
  const int h = local & 7, xy = local >> 3;
  const int bxy = (b0 + bloc)*64 + xy;
  const int lane = threadIdx.x;            // 0..63
  const int quad = lane >> 4, l15 = lane & 15;

  for (int i = lane; i < 169; i += 64) poss[i] = post[i*8 + h];
  for (int i = lane; i < 240; i += 64) Ks[784 + i] = 0;     // K pad rows
  for (int i = lane; i < 512; i += 64){                     // VT pad (ke 48..63)
    const int p = i >> 4, ke = 48 + (i & 15);
    VT[p*64 + ((((ke >> 3) ^ (p & 7)) & 7) << 3) + (ke & 7)] = 0;
  }
  { const u16* qsrc = qbuf + (size_t)(bxy*8 + h)*1568;      // Q rows -> PQ[qi][32]
    for (int i = lane; i < 196; i += 64)
      *(uint4*)&PQ[(i >> 2)*32 + (i & 3)*8] = *(const uint4*)(qsrc + (size_t)i*8);
    const uint4 z4 = make_uint4(0,0,0,0);
    for (int i = lane; i < 60; i += 64)                     // rows 49..63 zero
      *(uint4*)&PQ[1568 + i*8] = z4;
  }
  __syncthreads();

  // Q B-frags (persist across all z)
  h8 qf[4];
  #pragma unroll
  for (int nt = 0; nt < 4; ++nt)
    qf[nt] = *(const h8*)&PQ[(nt*16 + l15)*32 + quad*8];

  // bias C-in frags (persist): element (ke = mt*16+quad*4+reg, qi = nt*16+l15)
  fx4 bias[4][4];
  { int qa[4], qb[4];
    #pragma unroll
    for (int nt = 0; nt < 4; ++nt){
      const int qi = nt*16 + l15; qa[nt] = qi/7; qb[nt] = qi - qa[nt]*7;
    }
    #pragma unroll
    for (int mt = 0; mt < 4; ++mt)
      #pragma unroll
      for (int reg = 0; reg < 4; ++reg){
        const int ke = mt*16 + quad*4 + reg;
        const int ka = ke/7, kb = ke - ka*7;
        #pragma unroll
        for (int nt = 0; nt < 4; ++nt){
          const int qi = nt*16 + l15;
          float bv;
          if (ke > 48)      bv = -1e30f;
          else if (qi > 48) bv = 0.f;
          else              bv = poss[(qa[nt] - ka + 6)*13 + (qb[nt] - kb + 6)];
          bias[mt][nt][reg] = bv;
        }
      }
  }

  const size_t kvbase = ((size_t)(bloc*64 + xy)*8 + h)*6;
  float mprev[4], lsum[4];
  fx4 Oacc[2][4];
  #pragma unroll
  for (int nt = 0; nt < 4; ++nt){
    mprev[nt] = -1e30f; lsum[nt] = 0.f;
    Oacc[0][nt] = fx4{0,0,0,0}; Oacc[1][nt] = fx4{0,0,0,0};
  }

  for (int z = 0; z < 6; ++z){
    __syncthreads();   // previous phase's LDS reads complete
    { const uint4* ksrc = (const uint4*)((const u32*)kw + (kvbase + z)*784);
      for (int i = lane; i < 196; i += 64) ((uint4*)Ks)[i] = ksrc[i];
      const uint4* vsrc = (const uint4*)((const u32*)vm + (kvbase + z)*784);
      for (int i = lane; i < 196; i += 64){
        uint4 v4 = vsrc[i];
        const int ef = i >> 2, pb = (i & 3)*8;
        const int c0 = ef >> 3;
        u16* vt = VT + (ef & 7);
        vt[(pb+0)*64 + ((c0 ^ 0) << 3)] = (u16)(v4.x & 0xFFFFu);
        vt[(pb+1)*64 + ((c0 ^ 1) << 3)] = (u16)(v4.x >> 16);
        vt[(pb+2)*64 + ((c0 ^ 2) << 3)] = (u16)(v4.y & 0xFFFFu);
        vt[(pb+3)*64 + ((c0 ^ 3) << 3)] = (u16)(v4.y >> 16);
        vt[(pb+4)*64 + ((c0 ^ 4) << 3)] = (u16)(v4.z & 0xFFFFu);
        vt[(pb+5)*64 + ((c0 ^ 5) << 3)] = (u16)(v4.z >> 16);
        vt[(pb+6)*64 + ((c0 ^ 6) << 3)] = (u16)(v4.w & 0xFFFFu);
        vt[(pb+7)*64 + ((c0 ^ 7) << 3)] = (u16)(v4.w >> 16);
      } }
    __syncthreads();

    // ---- S^T = K·Q^T + bias (16 MFMA) ----
    h8 kf[4];
    #pragma unroll
    for (int mt = 0; mt < 4; ++mt)
      kf[mt] = *(const h8*)((const u16*)Ks + (mt*16 + l15)*32 + quad*8);
    fx4 S[4][4];
    #pragma unroll
    for (int mt = 0; mt < 4; ++mt)
      #pragma unroll
      for (int nt = 0; nt < 4; ++nt)
        S[mt][nt] = __builtin_amdgcn_mfma_f32_16x16x32_f16(kf[mt], qf[nt], bias[mt][nt], 0, 0, 0);

    // ---- online softmax per qi-column group nt ----
    #pragma unroll
    for (int nt = 0; nt < 4; ++nt){
      float cm = S[0][nt][0];
      #pragma unroll
      for (int mt = 0; mt < 4; ++mt)
        #pragma unroll
        for (int r = 0; r < 4; ++r) cm = fmaxf(cm, S[mt][nt][r]);
      cm = fmaxf(cm, __shfl_xor(cm, 16));
      cm = fmaxf(cm, __shfl_xor(cm, 32));
      const float mnew = fmaxf(mprev[nt], cm);
      const float alpha = __expf(mprev[nt] - mnew);
      mprev[nt] = mnew;
      float sum = 0.f;
      #pragma unroll
      for (int mt = 0; mt < 4; ++mt)
        #pragma unroll
        for (int r = 0; r < 4; ++r){
          float e = __expf(S[mt][nt][r] - mnew); S[mt][nt][r] = e; sum += e;
        }
      sum += __shfl_xor(sum, 16);
      sum += __shfl_xor(sum, 32);
      lsum[nt] = lsum[nt]*alpha + sum;
      #pragma unroll
      for (int r = 0; r < 4; ++r){ Oacc[0][nt][r] *= alpha; Oacc[1][nt][r] *= alpha; }
    }

    // ---- pack P^T into PQ (swizzled): ke chunk = mt*2 + (quad>>1) ----
    #pragma unroll
    for (int nt = 0; nt < 4; ++nt){
      const int qi = nt*16 + l15;
      u16* prow = &PQ[qi*64 + ((quad & 1) << 2)];
      #pragma unroll
      for (int mt = 0; mt < 4; ++mt){
        const int chk = (mt*2 + (quad >> 1)) ^ (l15 & 7);
        uint2 w;
        w.x = packh2(S[mt][nt][0], S[mt][nt][1]);
        w.y = packh2(S[mt][nt][2], S[mt][nt][3]);
        *(uint2*)(prow + (chk << 3)) = w;
      }
    }
    __syncthreads();

    // ---- O^T += V^T · P^T (16 MFMA over 2 k-steps) ----
    #pragma unroll
    for (int ks = 0; ks < 2; ++ks){
      h8 vf[2];
      #pragma unroll
      for (int m2 = 0; m2 < 2; ++m2)
        vf[m2] = *(const h8*)&VT[(m2*16 + l15)*64 + (((ks*4 + quad) ^ (l15 & 7)) << 3)];
      #pragma unroll
      for (int nt = 0; nt < 4; ++nt){
        h8 pf = *(const h8*)&PQ[(nt*16 + l15)*64 + (((ks*4 + quad) ^ (l15 & 7)) << 3)];
        Oacc[0][nt] = __builtin_amdgcn_mfma_f32_16x16x32_f16(vf[0], pf, Oacc[0][nt], 0, 0, 0);
        Oacc[1][nt] = __builtin_amdgcn_mfma_f32_16x16x32_f16(vf[1], pf, Oacc[1][nt], 0, 0, 0);
      }
    }
  }

  // ---- normalize + store via LDS roundtrip ----
  __syncthreads();
  #pragma unroll
  for (int nt = 0; nt < 4; ++nt){
    const int qi = nt*16 + l15;
    if (qi < 49){
      const float inv = 1.f / lsum[nt];
      #pragma unroll
      for (int m2 = 0; m2 < 2; ++m2){
        uint2 w;
        w.x = packh2(Oacc[m2][nt][0]*inv, Oacc[m2][nt][1]*inv);
        w.y = packh2(Oacc[m2][nt][2]*inv, Oacc[m2][nt][3]*inv);
        *(uint2*)&PQ[qi*32 + m2*16 + quad*4] = w;
      }
    }
  }
  __syncthreads();
  { u16* obase = aout + (size_t)bxy*12544 + h*32;
    for (int i = lane; i < 196; i += 64){
      const int r = i >> 2, c = (i & 3)*8;
      *(uint4*)(obase + (size_t)r*256 + c) = *(const uint4*)&PQ[r*32 + c];
    }
  }
}

// ---------------------------------------------------------------------------
// K4: final projection. A = attn out (f16), B = Wa[m0] fp32 [e][d], bias ba.
// ---------------------------------------------------------------------------
__global__ __launch_bounds__(256) void gemm_out(
    const u16* __restrict__ aout, const int* __restrict__ mode,
    const float* __restrict__ Wa, const float* __restrict__ ba,
    float* __restrict__ outp)
{
  __shared__ float As[16][68];
  __shared__ float Bs[16][68];
  const int nbase = blockIdx.x * 64;
  const int rowT  = blockIdx.y;           // 0..195
  const int b = rowT / 49, tile = rowT % 49;
  const int m0 = mode[b*6];
  const u16* Abase = aout + ((size_t)b*3136 + (size_t)tile*64)*256;
  const float* Wbase = Wa + (size_t)m0*65536;
  const int tid = threadIdx.x;
  const int tx = tid & 15, ty = tid >> 4;
  const int arow = tid >> 2, acol = (tid & 3)*4;
  const int bn = tid >> 2,  bk4 = (tid & 3)*4;
  float acc[4][4] = {};
  for (int k0 = 0; k0 < 256; k0 += 16) {
    uint2  ar = *(const uint2*)(Abase + (size_t)arow*256 + k0 + acol);
    float4 br = *(const float4*)(Wbase + (size_t)(nbase + bn)*256 + k0 + bk4);
    __syncthreads();
    { h2 lo = as_h2(ar.x), hi = as_h2(ar.y);
      As[acol+0][arow]=(float)lo.x; As[acol+1][arow]=(float)lo.y;
      As[acol+2][arow]=(float)hi.x; As[acol+3][arow]=(float)hi.y; }
    Bs[bk4+0][bn]=br.x; Bs[bk4+1][bn]=br.y; Bs[bk4+2][bn]=br.z; Bs[bk4+3][bn]=br.w;
    __syncthreads();
    #pragma unroll
    for (int kk = 0; kk < 16; ++kk){
      float4 a4 = *(const float4*)&As[kk][ty*4];
      float4 b4 = *(const float4*)&Bs[kk][tx*4];
      float ar_[4] = {a4.x,a4.y,a4.z,a4.w};
      float br_[4] = {b4.x,b4.y,b4.z,b4.w};
      #pragma unroll
      for (int i = 0; i < 4; ++i)
        #pragma unroll
        for (int j = 0; j < 4; ++j) acc[i][j] += ar_[i]*br_[j];
    }
  }
  const int colBase = nbase + tx*4;
  float bias[4];
  #pragma unroll
  for (int j = 0; j < 4; ++j) bias[j] = ba[m0*256 + colBase + j];
  #pragma unroll
  for (int i = 0; i < 4; ++i){
    int rowg = b*3136 + tile*64 + ty*4 + i;
    float4 o;
    o.x = acc[i][0] + bias[0];
    o.y = acc[i][1] + bias[1];
    o.z = acc[i][2] + bias[2];
    o.w = acc[i][3] + bias[3];
    *(float4*)(outp + (size_t)rowg*256 + colBase) = o;
  }
}

// ---------------------------------------------------------------------------
extern "C" void kernel_launch(void* const* d_in, const int* in_sizes, int n_in,
                              void* d_out, int out_size, void* d_ws, size_t ws_size,
                              hipStream_t stream)
{
  float* outp = (float*)d_out;
  const int FLAG_GRID = (out_size + 255)/256;

  if (n_in != 13) { flag_fill<<<FLAG_GRID,256,0,stream>>>(outp, out_size, 2000.f); return; }
  if (in_sizes[0] != 4*6*64*49*256) { flag_fill<<<FLAG_GRID,256,0,stream>>>(outp, out_size, 3000.f); return; }
  if (in_sizes[1] != 24) { flag_fill<<<FLAG_GRID,256,0,stream>>>(outp, out_size, 4000.f); return; }

  const size_t SZ_WFT  = (size_t)4*512*256*2;               //  1 MB (f16)
  const size_t SZ_BFF  = (size_t)4*512*sizeof(float);       //  8 KB
  const size_t SZ_Q    = (size_t)12544*256*2;               //  6.4 MB (f16)
  const size_t SZ_AOUT = (size_t)12544*256*2;               //  6.4 MB (f16)
  const size_t SZ_KW1  = (size_t)64*8*6*49*32*2;            //  9.63 MB / batch
  const size_t SZ_VM1  = SZ_KW1;                            //  unified layout
  const size_t FIXED   = SZ_WFT + SZ_BFF + SZ_Q + SZ_AOUT;
  if (ws_size < FIXED + SZ_KW1 + SZ_VM1) { flag_fill<<<FLAG_GRID,256,0,stream>>>(outp, out_size, 1000.f); return; }

  int nb = 1;
  if (ws_size >= FIXED + 4*(SZ_KW1 + SZ_VM1)) nb = 4;
  else if (ws_size >= FIXED + 2*(SZ_KW1 + SZ_VM1)) nb = 2;

  const float* x    = (const float*)d_in[0];
  const int*   mode = (const int*)d_in[1];
  const float* Wq   = (const float*)d_in[2];
  const float* bq   = (const float*)d_in[3];
  const float* Wk   = (const float*)d_in[4];
  const float* bk   = (const float*)d_in[5];
  const float* Wv   = (const float*)d_in[6];
  const float* bv   = (const float*)d_in[7];
  const float* Wa   = (const float*)d_in[8];
  const float* ba   = (const float*)d_in[9];
  const float* Ratt = (const float*)d_in[10];
  const float* Rmsg = (const float*)d_in[11];
  const float* post = (const float*)d_in[12];

  char* w = (char*)d_ws;
  u16* Wft   = (u16*)w;   w += SZ_WFT;
  float* bff = (float*)w; w += SZ_BFF;
  u16* qbuf  = (u16*)w;   w += SZ_Q;
  u16* aout  = (u16*)w;   w += SZ_AOUT;
  u16* kwbuf = (u16*)w;   w += (size_t)nb*SZ_KW1;
  u16* vmbuf = (u16*)w;   w += (size_t)nb*SZ_VM1;

  fuse_w<<<dim3(4,256), 512, 0, stream>>>(Wk, Wv, Ratt, Rmsg, Wft);
  fuse_b<<<4, 512, 0, stream>>>(bk, bv, Ratt, Rmsg, bff);
  gemm_q<<<dim3(4,196), 256, 0, stream>>>(x, mode, Wq, bq, qbuf);
  for (int b0 = 0; b0 < 4; b0 += nb) {
    gemm_kwv<<<nb*588, 256, 0, stream>>>(x, mode, Wft, bff, kwbuf, vmbuf, b0);
    attn_kernel<<<nb*512, 64, 0, stream>>>(qbuf, kwbuf, vmbuf, post, aout, b0);
  }
  gemm_out<<<dim3(4,196), 256, 0, stream>>>(aout, mode, Wa, ba, outp);
}

// Round 3
// 314.007 us; speedup vs baseline: 1.2740x; 1.0528x over previous
//
#include <hip/hip_runtime.h>

typedef unsigned short u16;
typedef unsigned int   u32;
typedef _Float16 f16;
typedef _Float16 h2  __attribute__((ext_vector_type(2)));
typedef _Float16 h8  __attribute__((ext_vector_type(8)));
typedef float    fx4 __attribute__((ext_vector_type(4)));

// ---- problem constants ----
// B=4 L=6 X=Y=8 -> 256 sites, W=49 window, D=256, h=8, dh=32
#define SCALE_Q 0.17677669529663687f

__device__ __forceinline__ u16 f2h_bits(float f){
  union{ f16 h; u16 u; } v; v.h = (f16)f; return v.u;
}
__device__ __forceinline__ u32 packh2(float a, float b){
  union{ h2 h; u32 u; } v; v.h = h2{(f16)a, (f16)b}; return v.u;
}
__device__ __forceinline__ h2 as_h2(u32 x){
  union{ u32 u; h2 h; } v; v.u = x; return v.h;
}
__device__ __forceinline__ h8 as_h8(uint4 u){
  union{ uint4 u; h8 h; } v; v.u = u; return v.h;
}

// diagnostic fill (fp32): encodes which runtime assumption failed
__global__ void flag_fill(float* out, int n, float v){
  int i = blockIdx.x*256 + threadIdx.x;
  if (i < n) out[i] = v;
}

// ---------------------------------------------------------------------------
// K0: fuse relation matrices into projection weights (fp32 in, f16 out).
// k-step-major layout  Wft[rel][k/32][n][k&31]  so that a wave's MFMA
// B-fragment load (16 n-rows x 32 k) is one CONTIGUOUS 1KB burst.
// ---------------------------------------------------------------------------
__global__ __launch_bounds__(512) void fuse_w(
    const float* __restrict__ Wk, const float* __restrict__ Wv,
    const float* __restrict__ Ratt, const float* __restrict__ Rmsg,
    u16* __restrict__ Wft)
{
  const int rel = blockIdx.x;      // 0..3
  const int d   = blockIdx.y;      // 0..255  (k index)
  const int n   = threadIdx.x;     // 0..511
  const int ml  = rel & 1;
  float acc = 0.f;
  if (n < 256) {
    const int h = n >> 5, p = n & 31;
    const float* wcol = Wk + (size_t)ml*65536 + (size_t)(h*32)*256 + d;
    const float* rrow = Ratt + ((size_t)(rel*8 + h)*32 + p)*32;
    #pragma unroll
    for (int q = 0; q < 32; ++q) acc += wcol[q*256] * rrow[q];
  } else {
    const int n2 = n - 256, h = n2 >> 5, qq = n2 & 31;
    const float* wcol = Wv + (size_t)ml*65536 + (size_t)(h*32)*256 + d;
    const float* rcol = Rmsg + ((size_t)(rel*8 + h)*32)*32 + qq;
    #pragma unroll
    for (int p2 = 0; p2 < 32; ++p2) acc += wcol[p2*256] * rcol[p2*32];
  }
  // [rel][d>>5][n][d&31]
  Wft[(size_t)rel*131072 + (size_t)(d >> 5)*16384 + (size_t)n*32 + (d & 31)] = f2h_bits(acc);
}

__global__ __launch_bounds__(512) void fuse_b(
    const float* __restrict__ bk, const float* __restrict__ bv,
    const float* __restrict__ Ratt, const float* __restrict__ Rmsg,
    float* __restrict__ bff)
{
  const int rel = blockIdx.x, n = threadIdx.x, ml = rel & 1;
  float acc = 0.f;
  if (n < 256) {
    const int h = n >> 5, p = n & 31;
    const float* rrow = Ratt + ((size_t)(rel*8 + h)*32 + p)*32;
    #pragma unroll
    for (int q = 0; q < 32; ++q) acc += bk[ml*256 + h*32 + q] * rrow[q];
  } else {
    const int n2 = n - 256, h = n2 >> 5, qq = n2 & 31;
    const float* rcol = Rmsg + ((size_t)(rel*8 + h)*32)*32 + qq;
    #pragma unroll
    for (int p2 = 0; p2 < 32; ++p2) acc += bv[ml*256 + h*32 + p2] * rcol[p2*32];
  }
  bff[rel*512 + n] = acc;
}

// ---------------------------------------------------------------------------
// K1 v6: fused kw / v_msg projection GEMM — MFMA (16x16x32 f16).
// BM=32, BN=512, grid = nb*588 (x fetched from HBM exactly once).
// v5's C++-level 2-stage pipeline was COLLAPSED by the compiler (VGPR=88
// proved the bnxt loads were sunk to their uses -> 64 serialized L2 loads).
// v6 pins the prefetch with asm volatile: two n-passes, each issuing all
// 32 B-fragment global_load_dwordx4 up front (128 VGPRs held, 32 loads in
// flight); pass-0 loads issued before the A-stage so the barrier's vmcnt
// drain hides them under the HBM A-fetch. K-loop is pure ds_read+MFMA.
// Epilogue unchanged; outputs kw/vm[bloc][xy][h][l][ef][p] (f16).
// ---------------------------------------------------------------------------
#define ASTRIDE 264   // u16 elements per LDS row (16B-aligned, conflict-light)

__global__ __launch_bounds__(256, 2) void gemm_kwv(
    const float* __restrict__ x, const int* __restrict__ mode,
    const u16* __restrict__ Wft, const float* __restrict__ bff,
    u16* __restrict__ kw, u16* __restrict__ vm, int b0)
{
  __shared__ u16 Smem[32*ASTRIDE];   // 16.9 KB: A-tile, then epilogue buffer
  const int rowT  = blockIdx.x;              // bloc*588 + l*98 + tile
  const int bloc = rowT / 588;
  const int rem  = rowT % 588;
  const int l = rem / 98, tile = rem % 98;
  const int b = b0 + bloc;
  const int rel = mode[b*6]*2 + mode[b*6 + l];
  const float* Abase = x + ((size_t)(b*6 + l)*3136 + (size_t)tile*32)*256;
  const int tid  = threadIdx.x;
  const int wave = tid >> 6, lane = tid & 63;
  const int quad = lane >> 4, l15 = lane & 15;

  // per-lane B base in k-step-major layout [rel][s][n][32]
  const u16* Bp = Wft + (size_t)rel*131072 + (size_t)((wave << 7) + l15)*32 + (quad << 3);

  // ---- pass-0 B prefetch: 32 pinned loads (n-tiles 0..3, all 8 k-steps).
  // Issued before the A-stage; the pre-barrier vmcnt drain hides them. ----
  uint4 breg[32];
  #pragma unroll
  for (int s = 0; s < 8; ++s)
    #pragma unroll
    for (int j = 0; j < 4; ++j){
      const u16* ap = Bp + (size_t)s*16384 + j*512;
      asm volatile("global_load_dwordx4 %0, %1, off" : "=v"(breg[s*4+j]) : "v"(ap));
    }

  // ---- stage A once: thread t loads row t>>3, cols (t&7)*32..+31 ----
  {
    const int r = tid >> 3, cseg = (tid & 7)*32;
    const float* src = Abase + (size_t)r*256 + cseg;
    u16* dst = &Smem[r*ASTRIDE + cseg];
    #pragma unroll
    for (int i = 0; i < 4; ++i){
      float4 f0 = *(const float4*)(src + i*8);
      float4 f1 = *(const float4*)(src + i*8 + 4);
      uint4 pk;
      pk.x = packh2(f0.x, f0.y); pk.y = packh2(f0.z, f0.w);
      pk.z = packh2(f1.x, f1.y); pk.w = packh2(f1.z, f1.w);
      *(uint4*)(dst + i*8) = pk;
    }
  }
  __syncthreads();

  fx4 acc[2][8];
  #pragma unroll
  for (int mt = 0; mt < 2; ++mt)
    #pragma unroll
    for (int j = 0; j < 8; ++j) acc[mt][j] = fx4{0,0,0,0};

  const u16* As0 = &Smem[l15*ASTRIDE + (quad << 3)];
  const u16* As1 = As0 + 16*ASTRIDE;

  // ---- pass 0 compute: pure LDS + MFMA ----
  asm volatile("s_waitcnt vmcnt(0)" ::: "memory");
  __builtin_amdgcn_sched_barrier(0);
  #pragma unroll
  for (int s = 0; s < 8; ++s){
    h8 af0 = *(const h8*)(As0 + s*32);
    h8 af1 = *(const h8*)(As1 + s*32);
    #pragma unroll
    for (int j = 0; j < 4; ++j){
      h8 bf = as_h8(breg[s*4+j]);
      acc[0][j] = __builtin_amdgcn_mfma_f32_16x16x32_f16(af0, bf, acc[0][j], 0, 0, 0);
      acc[1][j] = __builtin_amdgcn_mfma_f32_16x16x32_f16(af1, bf, acc[1][j], 0, 0, 0);
    }
  }

  // ---- pass-1 B prefetch (n-tiles 4..7) ----
  #pragma unroll
  for (int s = 0; s < 8; ++s)
    #pragma unroll
    for (int j = 0; j < 4; ++j){
      const u16* ap = Bp + (size_t)s*16384 + (size_t)(4 + j)*512;
      asm volatile("global_load_dwordx4 %0, %1, off" : "=v"(breg[s*4+j]) : "v"(ap));
    }
  asm volatile("s_waitcnt vmcnt(0)" ::: "memory");
  __builtin_amdgcn_sched_barrier(0);
  #pragma unroll
  for (int s = 0; s < 8; ++s){
    h8 af0 = *(const h8*)(As0 + s*32);
    h8 af1 = *(const h8*)(As1 + s*32);
    #pragma unroll
    for (int j = 0; j < 4; ++j){
      h8 bf = as_h8(breg[s*4+j]);
      acc[0][4+j] = __builtin_amdgcn_mfma_f32_16x16x32_f16(af0, bf, acc[0][4+j], 0, 0, 0);
      acc[1][4+j] = __builtin_amdgcn_mfma_f32_16x16x32_f16(af1, bf, acc[1][4+j], 0, 0, 0);
    }
  }

  // ---- epilogue: LDS transpose, two halves (kw = waves 0,1 / vm = 2,3) ----
  const int row_ = tid >> 3;        // 0..31
  const int hsel = tid & 7;         // 0..7
  const int r_g  = tile*32 + row_;  // 0..3135
  const int xy   = r_g / 49, ef = r_g - xy*49;

  #pragma unroll
  for (int half = 0; half < 2; ++half){
    __syncthreads();   // protect Smem (A-tile reads / previous half's reads)
    if ((wave >> 1) == half){
      #pragma unroll
      for (int j = 0; j < 8; ++j){
        const int n   = wave*128 + j*16 + l15;
        const int col = n & 255;
        const float bias = bff[rel*512 + n];
        #pragma unroll
        for (int mt = 0; mt < 2; ++mt){
          #pragma unroll
          for (int reg = 0; reg < 4; ++reg){
            const int row = mt*16 + quad*4 + reg;
            Smem[row*ASTRIDE + col] = f2h_bits(acc[mt][j][reg] + bias);
          }
        }
      }
    }
    __syncthreads();
    u16* dbuf = half ? vm : kw;
    u16* dst  = dbuf + ((((size_t)(bloc*64 + xy)*8 + hsel)*6 + l)*49 + ef)*32;
    const u16* srcl = &Smem[row_*ASTRIDE + hsel*32];
    uint4 v0 = *(const uint4*)(srcl);
    uint4 v1 = *(const uint4*)(srcl + 8);
    uint4 v2 = *(const uint4*)(srcl + 16);
    uint4 v3 = *(const uint4*)(srcl + 24);
    *(uint4*)(dst)      = v0;
    *(uint4*)(dst + 8)  = v1;
    *(uint4*)(dst + 16) = v2;
    *(uint4*)(dst + 24) = v3;
  }
}

// ---------------------------------------------------------------------------
// K2: q projection (l=0 only), VALU 4x4, f16 output.
// ---------------------------------------------------------------------------
__global__ __launch_bounds__(256) void gemm_q(
    const float* __restrict__ x, const int* __restrict__ mode,
    const float* __restrict__ Wq, const float* __restrict__ bq,
    u16* __restrict__ qbuf)
{
  __shared__ float As[16][68];
  __shared__ float Bs[16][68];
  const int nbase = blockIdx.x * 64;      // 0..192
  const int rowT  = blockIdx.y;           // 0..195
  const int b = rowT / 49, tile = rowT % 49;
  const int m0 = mode[b*6];
  const float* Abase = x + ((size_t)b*6*3136 + (size_t)tile*64)*256;
  const float* Wbase = Wq + (size_t)m0*65536;
  const int tid = threadIdx.x;
  const int tx = tid & 15, ty = tid >> 4;
  const int arow = tid >> 2, acol = (tid & 3)*4;
  const int bn = tid >> 2,  bk4 = (tid & 3)*4;
  float acc[4][4] = {};
  for (int k0 = 0; k0 < 256; k0 += 16) {
    float4 ar = *(const float4*)(Abase + (size_t)arow*256 + k0 + acol);
    float4 br = *(const float4*)(Wbase + (size_t)(nbase + bn)*256 + k0 + bk4);
    __syncthreads();
    As[acol+0][arow]=ar.x; As[acol+1][arow]=ar.y; As[acol+2][arow]=ar.z; As[acol+3][arow]=ar.w;
    Bs[bk4+0][bn]=br.x; Bs[bk4+1][bn]=br.y; Bs[bk4+2][bn]=br.z; Bs[bk4+3][bn]=br.w;
    __syncthreads();
    #pragma unroll
    for (int kk = 0; kk < 16; ++kk){
      float4 a4 = *(const float4*)&As[kk][ty*4];
      float4 b4 = *(const float4*)&Bs[kk][tx*4];
      float ar_[4] = {a4.x,a4.y,a4.z,a4.w};
      float br_[4] = {b4.x,b4.y,b4.z,b4.w};
      #pragma unroll
      for (int i = 0; i < 4; ++i)
        #pragma unroll
        for (int j = 0; j < 4; ++j) acc[i][j] += ar_[i]*br_[j];
    }
  }
  const int colBase = nbase + tx*4;
  const int h = colBase >> 5, p = colBase & 31;
  float bias[4];
  #pragma unroll
  for (int j = 0; j < 4; ++j) bias[j] = bq[m0*256 + colBase + j];
  #pragma unroll
  for (int i = 0; i < 4; ++i){
    int r = tile*64 + ty*4 + i;
    int xy = r / 49, ef = r - xy*49;
    size_t dst = (((size_t)(b*64 + xy)*8 + h)*49 + ef)*32 + p;
    ushort4 pk;
    pk.x = f2h_bits((acc[i][0]+bias[0])*SCALE_Q);
    pk.y = f2h_bits((acc[i][1]+bias[1])*SCALE_Q);
    pk.z = f2h_bits((acc[i][2]+bias[2])*SCALE_Q);
    pk.w = f2h_bits((acc[i][3]+bias[3])*SCALE_Q);
    *(ushort4*)(qbuf + dst) = pk;
  }
}

// ---------------------------------------------------------------------------
// K3 v6: attention — ONE WAVE per (bloc,xy,h), MFMA-based.
// S^T = K·Q^T via 16x16x32_f16 (A = K rows, B = Q rows, C-in = pos-bias held
// in 64 VGPRs; ke>=49 masked with -1e30 in C-in; Q/K pad rows zeroed).
// Softmax per qi-column: column qi lives at lane&15, reduce over 4 regs x
// 4 mt-tiles in-lane + 2 shfl_xor across quads. Online m/l per column.
// P^T staged to XOR-swizzled LDS (b64 writes / conflict-free b128 reads).
// O^T += V^T·P^T via MFMA; V^T built by the staging scatter-transpose into a
// chunk-XOR-swizzled [p][ke] buffer (conflict-free b128 A-frag reads).
// Output normalized and stored via LDS roundtrip (coalesced uint4 stores).
// ---------------------------------------------------------------------------
__global__ __launch_bounds__(64) void attn_kernel(
    const u16* __restrict__ qbuf, const u16* __restrict__ kw,
    const u16* __restrict__ vm,   const float* __restrict__ post,
    u16* __restrict__ aout, int b0)
{
  __shared__ u32 Ks[64*16];     // K rows [ke][p] (ke 49..63 zeroed once)   4KB
  __shared__ u16 VT[32*64];     // V^T [p][ke], ke-chunk XOR-swizzled       4KB
  __shared__ u16 PQ[64*64];     // Q staging [qi][32] -> P^T [qi][ke] swz   8KB
  __shared__ float poss[169];

  const int bloc  = blockIdx.x >> 9;
  const int local = blockIdx.x & 511;      // xy*8+h
  const int h = local & 7, xy = local >> 3;
  const int bxy = (b0 + bloc)*64 + xy;
  const int lane = threadIdx.x;            // 0..63
  const int quad = lane >> 4, l15 = lane & 15;

  for (int i = lane; i < 169; i += 64) poss[i] = post[i*8 + h];
  for (int i = lane; i < 240; i += 64) Ks[784 + i] = 0;     // K pad rows
  for (int i = lane; i < 512; i += 64){                     // VT pad (ke 48..63)
    const int p = i >> 4, ke = 48 + (i & 15);
    VT[p*64 + ((((ke >> 3) ^ (p & 7)) & 7) << 3) + (ke & 7)] = 0;
  }
  { const u16* qsrc = qbuf + (size_t)(bxy*8 + h)*1568;      // Q rows -> PQ[qi][32]
    for (int i = lane; i < 196; i += 64)
      *(uint4*)&PQ[(i >> 2)*32 + (i & 3)*8] = *(const uint4*)(qsrc + (size_t)i*8);
    const uint4 z4 = make_uint4(0,0,0,0);
    for (int i = lane; i < 60; i += 64)                     // rows 49..63 zero
      *(uint4*)&PQ[1568 + i*8] = z4;
  }
  __syncthreads();

  // Q B-frags (persist across all z)
  h8 qf[4];
  #pragma unroll
  for (int nt = 0; nt < 4; ++nt)
    qf[nt] = *(const h8*)&PQ[(nt*16 + l15)*32 + quad*8];

  // bias C-in frags (persist): element (ke = mt*16+quad*4+reg, qi = nt*16+l15)
  fx4 bias[4][4];
  { int qa[4], qb[4];
    #pragma unroll
    for (int nt = 0; nt < 4; ++nt){
      const int qi = nt*16 + l15; qa[nt] = qi/7; qb[nt] = qi - qa[nt]*7;
    }
    #pragma unroll
    for (int mt = 0; mt < 4; ++mt)
      #pragma unroll
      for (int reg = 0; reg < 4; ++reg){
        const int ke = mt*16 + quad*4 + reg;
        const int ka = ke/7, kb = ke - ka*7;
        #pragma unroll
        for (int nt = 0; nt < 4; ++nt){
          const int qi = nt*16 + l15;
          float bv;
          if (ke > 48)      bv = -1e30f;
          else if (qi > 48) bv = 0.f;
          else              bv = poss[(qa[nt] - ka + 6)*13 + (qb[nt] - kb + 6)];
          bias[mt][nt][reg] = bv;
        }
      }
  }

  const size_t kvbase = ((size_t)(bloc*64 + xy)*8 + h)*6;
  float mprev[4], lsum[4];
  fx4 Oacc[2][4];
  #pragma unroll
  for (int nt = 0; nt < 4; ++nt){
    mprev[nt] = -1e30f; lsum[nt] = 0.f;
    Oacc[0][nt] = fx4{0,0,0,0}; Oacc[1][nt] = fx4{0,0,0,0};
  }

  for (int z = 0; z < 6; ++z){
    __syncthreads();   // previous phase's LDS reads complete
    { const uint4* ksrc = (const uint4*)((const u32*)kw + (kvbase + z)*784);
      for (int i = lane; i < 196; i += 64) ((uint4*)Ks)[i] = ksrc[i];
      const uint4* vsrc = (const uint4*)((const u32*)vm + (kvbase + z)*784);
      for (int i = lane; i < 196; i += 64){
        uint4 v4 = vsrc[i];
        const int ef = i >> 2, pb = (i & 3)*8;
        const int c0 = ef >> 3;
        u16* vt = VT + (ef & 7);
        vt[(pb+0)*64 + ((c0 ^ 0) << 3)] = (u16)(v4.x & 0xFFFFu);
        vt[(pb+1)*64 + ((c0 ^ 1) << 3)] = (u16)(v4.x >> 16);
        vt[(pb+2)*64 + ((c0 ^ 2) << 3)] = (u16)(v4.y & 0xFFFFu);
        vt[(pb+3)*64 + ((c0 ^ 3) << 3)] = (u16)(v4.y >> 16);
        vt[(pb+4)*64 + ((c0 ^ 4) << 3)] = (u16)(v4.z & 0xFFFFu);
        vt[(pb+5)*64 + ((c0 ^ 5) << 3)] = (u16)(v4.z >> 16);
        vt[(pb+6)*64 + ((c0 ^ 6) << 3)] = (u16)(v4.w & 0xFFFFu);
        vt[(pb+7)*64 + ((c0 ^ 7) << 3)] = (u16)(v4.w >> 16);
      } }
    __syncthreads();

    // ---- S^T = K·Q^T + bias (16 MFMA) ----
    h8 kf[4];
    #pragma unroll
    for (int mt = 0; mt < 4; ++mt)
      kf[mt] = *(const h8*)((const u16*)Ks + (mt*16 + l15)*32 + quad*8);
    fx4 S[4][4];
    #pragma unroll
    for (int mt = 0; mt < 4; ++mt)
      #pragma unroll
      for (int nt = 0; nt < 4; ++nt)
        S[mt][nt] = __builtin_amdgcn_mfma_f32_16x16x32_f16(kf[mt], qf[nt], bias[mt][nt], 0, 0, 0);

    // ---- online softmax per qi-column group nt ----
    #pragma unroll
    for (int nt = 0; nt < 4; ++nt){
      float cm = S[0][nt][0];
      #pragma unroll
      for (int mt = 0; mt < 4; ++mt)
        #pragma unroll
        for (int r = 0; r < 4; ++r) cm = fmaxf(cm, S[mt][nt][r]);
      cm = fmaxf(cm, __shfl_xor(cm, 16));
      cm = fmaxf(cm, __shfl_xor(cm, 32));
      const float mnew = fmaxf(mprev[nt], cm);
      const float alpha = __expf(mprev[nt] - mnew);
      mprev[nt] = mnew;
      float sum = 0.f;
      #pragma unroll
      for (int mt = 0; mt < 4; ++mt)
        #pragma unroll
        for (int r = 0; r < 4; ++r){
          float e = __expf(S[mt][nt][r] - mnew); S[mt][nt][r] = e; sum += e;
        }
      sum += __shfl_xor(sum, 16);
      sum += __shfl_xor(sum, 32);
      lsum[nt] = lsum[nt]*alpha + sum;
      #pragma unroll
      for (int r = 0; r < 4; ++r){ Oacc[0][nt][r] *= alpha; Oacc[1][nt][r] *= alpha; }
    }

    // ---- pack P^T into PQ (swizzled): ke chunk = mt*2 + (quad>>1) ----
    #pragma unroll
    for (int nt = 0; nt < 4; ++nt){
      const int qi = nt*16 + l15;
      u16* prow = &PQ[qi*64 + ((quad & 1) << 2)];
      #pragma unroll
      for (int mt = 0; mt < 4; ++mt){
        const int chk = (mt*2 + (quad >> 1)) ^ (l15 & 7);
        uint2 w;
        w.x = packh2(S[mt][nt][0], S[mt][nt][1]);
        w.y = packh2(S[mt][nt][2], S[mt][nt][3]);
        *(uint2*)(prow + (chk << 3)) = w;
      }
    }
    __syncthreads();

    // ---- O^T += V^T · P^T (16 MFMA over 2 k-steps) ----
    #pragma unroll
    for (int ks = 0; ks < 2; ++ks){
      h8 vf[2];
      #pragma unroll
      for (int m2 = 0; m2 < 2; ++m2)
        vf[m2] = *(const h8*)&VT[(m2*16 + l15)*64 + (((ks*4 + quad) ^ (l15 & 7)) << 3)];
      #pragma unroll
      for (int nt = 0; nt < 4; ++nt){
        h8 pf = *(const h8*)&PQ[(nt*16 + l15)*64 + (((ks*4 + quad) ^ (l15 & 7)) << 3)];
        Oacc[0][nt] = __builtin_amdgcn_mfma_f32_16x16x32_f16(vf[0], pf, Oacc[0][nt], 0, 0, 0);
        Oacc[1][nt] = __builtin_amdgcn_mfma_f32_16x16x32_f16(vf[1], pf, Oacc[1][nt], 0, 0, 0);
      }
    }
  }

  // ---- normalize + store via LDS roundtrip ----
  __syncthreads();
  #pragma unroll
  for (int nt = 0; nt < 4; ++nt){
    const int qi = nt*16 + l15;
    if (qi < 49){
      const float inv = 1.f / lsum[nt];
      #pragma unroll
      for (int m2 = 0; m2 < 2; ++m2){
        uint2 w;
        w.x = packh2(Oacc[m2][nt][0]*inv, Oacc[m2][nt][1]*inv);
        w.y = packh2(Oacc[m2][nt][2]*inv, Oacc[m2][nt][3]*inv);
        *(uint2*)&PQ[qi*32 + m2*16 + quad*4] = w;
      }
    }
  }
  __syncthreads();
  { u16* obase = aout + (size_t)bxy*12544 + h*32;
    for (int i = lane; i < 196; i += 64){
      const int r = i >> 2, c = (i & 3)*8;
      *(uint4*)(obase + (size_t)r*256 + c) = *(const uint4*)&PQ[r*32 + c];
    }
  }
}

// ---------------------------------------------------------------------------
// K4: final projection. A = attn out (f16), B = Wa[m0] fp32 [e][d], bias ba.
// ---------------------------------------------------------------------------
__global__ __launch_bounds__(256) void gemm_out(
    const u16* __restrict__ aout, const int* __restrict__ mode,
    const float* __restrict__ Wa, const float* __restrict__ ba,
    float* __restrict__ outp)
{
  __shared__ float As[16][68];
  __shared__ float Bs[16][68];
  const int nbase = blockIdx.x * 64;
  const int rowT  = blockIdx.y;           // 0..195
  const int b = rowT / 49, tile = rowT % 49;
  const int m0 = mode[b*6];
  const u16* Abase = aout + ((size_t)b*3136 + (size_t)tile*64)*256;
  const float* Wbase = Wa + (size_t)m0*65536;
  const int tid = threadIdx.x;
  const int tx = tid & 15, ty = tid >> 4;
  const int arow = tid >> 2, acol = (tid & 3)*4;
  const int bn = tid >> 2,  bk4 = (tid & 3)*4;
  float acc[4][4] = {};
  for (int k0 = 0; k0 < 256; k0 += 16) {
    uint2  ar = *(const uint2*)(Abase + (size_t)arow*256 + k0 + acol);
    float4 br = *(const float4*)(Wbase + (size_t)(nbase + bn)*256 + k0 + bk4);
    __syncthreads();
    { h2 lo = as_h2(ar.x), hi = as_h2(ar.y);
      As[acol+0][arow]=(float)lo.x; As[acol+1][arow]=(float)lo.y;
      As[acol+2][arow]=(float)hi.x; As[acol+3][arow]=(float)hi.y; }
    Bs[bk4+0][bn]=br.x; Bs[bk4+1][bn]=br.y; Bs[bk4+2][bn]=br.z; Bs[bk4+3][bn]=br.w;
    __syncthreads();
    #pragma unroll
    for (int kk = 0; kk < 16; ++kk){
      float4 a4 = *(const float4*)&As[kk][ty*4];
      float4 b4 = *(const float4*)&Bs[kk][tx*4];
      float ar_[4] = {a4.x,a4.y,a4.z,a4.w};
      float br_[4] = {b4.x,b4.y,b4.z,b4.w};
      #pragma unroll
      for (int i = 0; i < 4; ++i)
        #pragma unroll
        for (int j = 0; j < 4; ++j) acc[i][j] += ar_[i]*br_[j];
    }
  }
  const int colBase = nbase + tx*4;
  float bias[4];
  #pragma unroll
  for (int j = 0; j < 4; ++j) bias[j] = ba[m0*256 + colBase + j];
  #pragma unroll
  for (int i = 0; i < 4; ++i){
    int rowg = b*3136 + tile*64 + ty*4 + i;
    float4 o;
    o.x = acc[i][0] + bias[0];
    o.y = acc[i][1] + bias[1];
    o.z = acc[i][2] + bias[2];
    o.w = acc[i][3] + bias[3];
    *(float4*)(outp + (size_t)rowg*256 + colBase) = o;
  }
}

// ---------------------------------------------------------------------------
extern "C" void kernel_launch(void* const* d_in, const int* in_sizes, int n_in,
                              void* d_out, int out_size, void* d_ws, size_t ws_size,
                              hipStream_t stream)
{
  float* outp = (float*)d_out;
  const int FLAG_GRID = (out_size + 255)/256;

  if (n_in != 13) { flag_fill<<<FLAG_GRID,256,0,stream>>>(outp, out_size, 2000.f); return; }
  if (in_sizes[0] != 4*6*64*49*256) { flag_fill<<<FLAG_GRID,256,0,stream>>>(outp, out_size, 3000.f); return; }
  if (in_sizes[1] != 24) { flag_fill<<<FLAG_GRID,256,0,stream>>>(outp, out_size, 4000.f); return; }

  const size_t SZ_WFT  = (size_t)4*512*256*2;               //  1 MB (f16)
  const size_t SZ_BFF  = (size_t)4*512*sizeof(float);       //  8 KB
  const size_t SZ_Q    = (size_t)12544*256*2;               //  6.4 MB (f16)
  const size_t SZ_AOUT = (size_t)12544*256*2;               //  6.4 MB (f16)
  const size_t SZ_KW1  = (size_t)64*8*6*49*32*2;            //  9.63 MB / batch
  const size_t SZ_VM1  = SZ_KW1;                            //  unified layout
  const size_t FIXED   = SZ_WFT + SZ_BFF + SZ_Q + SZ_AOUT;
  if (ws_size < FIXED + SZ_KW1 + SZ_VM1) { flag_fill<<<FLAG_GRID,256,0,stream>>>(outp, out_size, 1000.f); return; }

  int nb = 1;
  if (ws_size >= FIXED + 4*(SZ_KW1 + SZ_VM1)) nb = 4;
  else if (ws_size >= FIXED + 2*(SZ_KW1 + SZ_VM1)) nb = 2;

  const float* x    = (const float*)d_in[0];
  const int*   mode = (const int*)d_in[1];
  const float* Wq   = (const float*)d_in[2];
  const float* bq   = (const float*)d_in[3];
  const float* Wk   = (const float*)d_in[4];
  const float* bk   = (const float*)d_in[5];
  const float* Wv   = (const float*)d_in[6];
  const float* bv   = (const float*)d_in[7];
  const float* Wa   = (const float*)d_in[8];
  const float* ba   = (const float*)d_in[9];
  const float* Ratt = (const float*)d_in[10];
  const float* Rmsg = (const float*)d_in[11];
  const float* post = (const float*)d_in[12];

  char* w = (char*)d_ws;
  u16* Wft   = (u16*)w;   w += SZ_WFT;
  float* bff = (float*)w; w += SZ_BFF;
  u16* qbuf  = (u16*)w;   w += SZ_Q;
  u16* aout  = (u16*)w;   w += SZ_AOUT;
  u16* kwbuf = (u16*)w;   w += (size_t)nb*SZ_KW1;
  u16* vmbuf = (u16*)w;   w += (size_t)nb*SZ_VM1;

  fuse_w<<<dim3(4,256), 512, 0, stream>>>(Wk, Wv, Ratt, Rmsg, Wft);
  fuse_b<<<4, 512, 0, stream>>>(bk, bv, Ratt, Rmsg, bff);
  gemm_q<<<dim3(4,196), 256, 0, stream>>>(x, mode, Wq, bq, qbuf);
  for (int b0 = 0; b0 < 4; b0 += nb) {
    gemm_kwv<<<nb*588, 256, 0, stream>>>(x, mode, Wft, bff, kwbuf, vmbuf, b0);
    attn_kernel<<<nb*512, 64, 0, stream>>>(qbuf, kwbuf, vmbuf, post, aout, b0);
  }
  gemm_out<<<dim3(4,196), 256, 0, stream>>>(aout, mode, Wa, ba, outp);
}

// Round 4
// 281.654 us; speedup vs baseline: 1.4204x; 1.1149x over previous
//
#include <hip/hip_runtime.h>

typedef unsigned short u16;
typedef unsigned int   u32;
typedef _Float16 f16;
typedef _Float16 h2  __attribute__((ext_vector_type(2)));
typedef _Float16 h8  __attribute__((ext_vector_type(8)));
typedef float    fx4 __attribute__((ext_vector_type(4)));

// ---- problem constants ----
// B=4 L=6 X=Y=8 -> 256 sites, W=49 window, D=256, h=8, dh=32
#define SCALE_Q 0.17677669529663687f

__device__ __forceinline__ u16 f2h_bits(float f){
  union{ f16 h; u16 u; } v; v.h = (f16)f; return v.u;
}
__device__ __forceinline__ u32 packh2(float a, float b){
  union{ h2 h; u32 u; } v; v.h = h2{(f16)a, (f16)b}; return v.u;
}
__device__ __forceinline__ h2 as_h2(u32 x){
  union{ u32 u; h2 h; } v; v.u = x; return v.h;
}
__device__ __forceinline__ h8 as_h8(uint4 u){
  union{ uint4 u; h8 h; } v; v.u = u; return v.h;
}

// diagnostic fill (fp32): encodes which runtime assumption failed
__global__ void flag_fill(float* out, int n, float v){
  int i = blockIdx.x*256 + threadIdx.x;
  if (i < n) out[i] = v;
}

// ---------------------------------------------------------------------------
// K0: fuse relation matrices into projection weights (fp32 in, f16 out).
// k-step-major layout  Wft[rel][k/32][n][k&31]  so that a wave's MFMA
// B-fragment load (16 n-rows x 32 k) is one CONTIGUOUS 1KB burst.
// ---------------------------------------------------------------------------
__global__ __launch_bounds__(512) void fuse_w(
    const float* __restrict__ Wk, const float* __restrict__ Wv,
    const float* __restrict__ Ratt, const float* __restrict__ Rmsg,
    u16* __restrict__ Wft)
{
  const int rel = blockIdx.x;      // 0..3
  const int d   = blockIdx.y;      // 0..255  (k index)
  const int n   = threadIdx.x;     // 0..511
  const int ml  = rel & 1;
  float acc = 0.f;
  if (n < 256) {
    const int h = n >> 5, p = n & 31;
    const float* wcol = Wk + (size_t)ml*65536 + (size_t)(h*32)*256 + d;
    const float* rrow = Ratt + ((size_t)(rel*8 + h)*32 + p)*32;
    #pragma unroll
    for (int q = 0; q < 32; ++q) acc += wcol[q*256] * rrow[q];
  } else {
    const int n2 = n - 256, h = n2 >> 5, qq = n2 & 31;
    const float* wcol = Wv + (size_t)ml*65536 + (size_t)(h*32)*256 + d;
    const float* rcol = Rmsg + ((size_t)(rel*8 + h)*32)*32 + qq;
    #pragma unroll
    for (int p2 = 0; p2 < 32; ++p2) acc += wcol[p2*256] * rcol[p2*32];
  }
  // [rel][d>>5][n][d&31]
  Wft[(size_t)rel*131072 + (size_t)(d >> 5)*16384 + (size_t)n*32 + (d & 31)] = f2h_bits(acc);
}

__global__ __launch_bounds__(512) void fuse_b(
    const float* __restrict__ bk, const float* __restrict__ bv,
    const float* __restrict__ Ratt, const float* __restrict__ Rmsg,
    float* __restrict__ bff)
{
  const int rel = blockIdx.x, n = threadIdx.x, ml = rel & 1;
  float acc = 0.f;
  if (n < 256) {
    const int h = n >> 5, p = n & 31;
    const float* rrow = Ratt + ((size_t)(rel*8 + h)*32 + p)*32;
    #pragma unroll
    for (int q = 0; q < 32; ++q) acc += bk[ml*256 + h*32 + q] * rrow[q];
  } else {
    const int n2 = n - 256, h = n2 >> 5, qq = n2 & 31;
    const float* rcol = Rmsg + ((size_t)(rel*8 + h)*32)*32 + qq;
    #pragma unroll
    for (int p2 = 0; p2 < 32; ++p2) acc += bv[ml*256 + h*32 + p2] * rcol[p2*32];
  }
  bff[rel*512 + n] = acc;
}

// ---------------------------------------------------------------------------
// K0b: cast Wq (SCALE_Q folded) and Wa to k-step-major f16 [type][s][n][32]
// for the MFMA q / out projection kernels.
// ---------------------------------------------------------------------------
__global__ __launch_bounds__(512) void fuse_qo(
    const float* __restrict__ Wq, const float* __restrict__ Wa,
    u16* __restrict__ Wqf, u16* __restrict__ Waf)
{
  const int t = blockIdx.x;   // type 0..1
  const int d = blockIdx.y;   // 0..255 (k index)
  const int n = threadIdx.x;  // 0..511
  if (n < 256){
    float v = Wq[(size_t)t*65536 + (size_t)n*256 + d] * SCALE_Q;
    Wqf[(size_t)t*65536 + (size_t)(d >> 5)*8192 + (size_t)n*32 + (d & 31)] = f2h_bits(v);
  } else {
    const int e = n - 256;
    float v = Wa[(size_t)t*65536 + (size_t)e*256 + d];
    Waf[(size_t)t*65536 + (size_t)(d >> 5)*8192 + (size_t)e*32 + (d & 31)] = f2h_bits(v);
  }
}

// ---------------------------------------------------------------------------
// K1 v6: fused kw / v_msg projection GEMM — MFMA (16x16x32 f16).
// BM=32, BN=512, grid = nb*588 (x fetched from HBM exactly once).
// asm-volatile-pinned B prefetch (2 n-passes x 32 loads); pass-0 loads hide
// under the A-stage HBM fetch. Epilogue via LDS transpose; outputs
// kw/vm[bloc][xy][h][l][ef][p] (f16).
// ---------------------------------------------------------------------------
#define ASTRIDE 264   // u16 elements per LDS row (16B-aligned, conflict-light)

__global__ __launch_bounds__(256, 2) void gemm_kwv(
    const float* __restrict__ x, const int* __restrict__ mode,
    const u16* __restrict__ Wft, const float* __restrict__ bff,
    u16* __restrict__ kw, u16* __restrict__ vm, int b0)
{
  __shared__ u16 Smem[32*ASTRIDE];   // 16.9 KB: A-tile, then epilogue buffer
  const int rowT  = blockIdx.x;              // bloc*588 + l*98 + tile
  const int bloc = rowT / 588;
  const int rem  = rowT % 588;
  const int l = rem / 98, tile = rem % 98;
  const int b = b0 + bloc;
  const int rel = mode[b*6]*2 + mode[b*6 + l];
  const float* Abase = x + ((size_t)(b*6 + l)*3136 + (size_t)tile*32)*256;
  const int tid  = threadIdx.x;
  const int wave = tid >> 6, lane = tid & 63;
  const int quad = lane >> 4, l15 = lane & 15;

  // per-lane B base in k-step-major layout [rel][s][n][32]
  const u16* Bp = Wft + (size_t)rel*131072 + (size_t)((wave << 7) + l15)*32 + (quad << 3);

  // ---- pass-0 B prefetch: 32 pinned loads (n-tiles 0..3, all 8 k-steps) ----
  uint4 breg[32];
  #pragma unroll
  for (int s = 0; s < 8; ++s)
    #pragma unroll
    for (int j = 0; j < 4; ++j){
      const u16* ap = Bp + (size_t)s*16384 + j*512;
      asm volatile("global_load_dwordx4 %0, %1, off" : "=v"(breg[s*4+j]) : "v"(ap));
    }

  // ---- stage A once: thread t loads row t>>3, cols (t&7)*32..+31 ----
  {
    const int r = tid >> 3, cseg = (tid & 7)*32;
    const float* src = Abase + (size_t)r*256 + cseg;
    u16* dst = &Smem[r*ASTRIDE + cseg];
    #pragma unroll
    for (int i = 0; i < 4; ++i){
      float4 f0 = *(const float4*)(src + i*8);
      float4 f1 = *(const float4*)(src + i*8 + 4);
      uint4 pk;
      pk.x = packh2(f0.x, f0.y); pk.y = packh2(f0.z, f0.w);
      pk.z = packh2(f1.x, f1.y); pk.w = packh2(f1.z, f1.w);
      *(uint4*)(dst + i*8) = pk;
    }
  }
  __syncthreads();

  fx4 acc[2][8];
  #pragma unroll
  for (int mt = 0; mt < 2; ++mt)
    #pragma unroll
    for (int j = 0; j < 8; ++j) acc[mt][j] = fx4{0,0,0,0};

  const u16* As0 = &Smem[l15*ASTRIDE + (quad << 3)];
  const u16* As1 = As0 + 16*ASTRIDE;

  // ---- pass 0 compute: pure LDS + MFMA ----
  asm volatile("s_waitcnt vmcnt(0)" ::: "memory");
  __builtin_amdgcn_sched_barrier(0);
  #pragma unroll
  for (int s = 0; s < 8; ++s){
    h8 af0 = *(const h8*)(As0 + s*32);
    h8 af1 = *(const h8*)(As1 + s*32);
    #pragma unroll
    for (int j = 0; j < 4; ++j){
      h8 bf = as_h8(breg[s*4+j]);
      acc[0][j] = __builtin_amdgcn_mfma_f32_16x16x32_f16(af0, bf, acc[0][j], 0, 0, 0);
      acc[1][j] = __builtin_amdgcn_mfma_f32_16x16x32_f16(af1, bf, acc[1][j], 0, 0, 0);
    }
  }

  // ---- pass-1 B prefetch (n-tiles 4..7) ----
  #pragma unroll
  for (int s = 0; s < 8; ++s)
    #pragma unroll
    for (int j = 0; j < 4; ++j){
      const u16* ap = Bp + (size_t)s*16384 + (size_t)(4 + j)*512;
      asm volatile("global_load_dwordx4 %0, %1, off" : "=v"(breg[s*4+j]) : "v"(ap));
    }
  asm volatile("s_waitcnt vmcnt(0)" ::: "memory");
  __builtin_amdgcn_sched_barrier(0);
  #pragma unroll
  for (int s = 0; s < 8; ++s){
    h8 af0 = *(const h8*)(As0 + s*32);
    h8 af1 = *(const h8*)(As1 + s*32);
    #pragma unroll
    for (int j = 0; j < 4; ++j){
      h8 bf = as_h8(breg[s*4+j]);
      acc[0][4+j] = __builtin_amdgcn_mfma_f32_16x16x32_f16(af0, bf, acc[0][4+j], 0, 0, 0);
      acc[1][4+j] = __builtin_amdgcn_mfma_f32_16x16x32_f16(af1, bf, acc[1][4+j], 0, 0, 0);
    }
  }

  // ---- epilogue: LDS transpose, two halves (kw = waves 0,1 / vm = 2,3) ----
  const int row_ = tid >> 3;        // 0..31
  const int hsel = tid & 7;         // 0..7
  const int r_g  = tile*32 + row_;  // 0..3135
  const int xy   = r_g / 49, ef = r_g - xy*49;

  #pragma unroll
  for (int half = 0; half < 2; ++half){
    __syncthreads();   // protect Smem (A-tile reads / previous half's reads)
    if ((wave >> 1) == half){
      #pragma unroll
      for (int j = 0; j < 8; ++j){
        const int n   = wave*128 + j*16 + l15;
        const int col = n & 255;
        const float bias = bff[rel*512 + n];
        #pragma unroll
        for (int mt = 0; mt < 2; ++mt){
          #pragma unroll
          for (int reg = 0; reg < 4; ++reg){
            const int row = mt*16 + quad*4 + reg;
            Smem[row*ASTRIDE + col] = f2h_bits(acc[mt][j][reg] + bias);
          }
        }
      }
    }
    __syncthreads();
    u16* dbuf = half ? vm : kw;
    u16* dst  = dbuf + ((((size_t)(bloc*64 + xy)*8 + hsel)*6 + l)*49 + ef)*32;
    const u16* srcl = &Smem[row_*ASTRIDE + hsel*32];
    uint4 v0 = *(const uint4*)(srcl);
    uint4 v1 = *(const uint4*)(srcl + 8);
    uint4 v2 = *(const uint4*)(srcl + 16);
    uint4 v3 = *(const uint4*)(srcl + 24);
    *(uint4*)(dst)      = v0;
    *(uint4*)(dst + 8)  = v1;
    *(uint4*)(dst + 16) = v2;
    *(uint4*)(dst + 24) = v3;
  }
}

// ---------------------------------------------------------------------------
// K2 v2: q projection (l=0 only) — MFMA, kwv template. BM=32, BN=256,
// grid = 4*98. B = Wqf[m0] (SCALE_Q folded), all 32 B-frag loads pinned in
// flight before the A-stage. Epilogue: LDS transpose -> qbuf f16
// [bxy][h][ef][p], bias bq*SCALE_Q added.
// ---------------------------------------------------------------------------
__global__ __launch_bounds__(256, 2) void gemm_qp(
    const float* __restrict__ x, const int* __restrict__ mode,
    const u16* __restrict__ Wqf, const float* __restrict__ bq,
    u16* __restrict__ qbuf)
{
  __shared__ u16 Smem[32*ASTRIDE];
  const int rowT = blockIdx.x;       // b*98 + tile
  const int b = rowT / 98, tile = rowT % 98;
  const int m0 = mode[b*6];
  const float* Abase = x + ((size_t)(b*6)*3136 + (size_t)tile*32)*256;
  const int tid = threadIdx.x;
  const int wave = tid >> 6, lane = tid & 63;
  const int quad = lane >> 4, l15 = lane & 15;

  // B base: [m0][s][n][32], wave owns cols wave*64..+64
  const u16* Bp = Wqf + (size_t)m0*65536 + (size_t)((wave << 6) + l15)*32 + (quad << 3);
  uint4 breg[32];
  #pragma unroll
  for (int s = 0; s < 8; ++s)
    #pragma unroll
    for (int j = 0; j < 4; ++j){
      const u16* ap = Bp + (size_t)s*8192 + j*512;
      asm volatile("global_load_dwordx4 %0, %1, off" : "=v"(breg[s*4+j]) : "v"(ap));
    }

  // A-stage fp32 -> f16
  {
    const int r = tid >> 3, cseg = (tid & 7)*32;
    const float* src = Abase + (size_t)r*256 + cseg;
    u16* dst = &Smem[r*ASTRIDE + cseg];
    #pragma unroll
    for (int i = 0; i < 4; ++i){
      float4 f0 = *(const float4*)(src + i*8);
      float4 f1 = *(const float4*)(src + i*8 + 4);
      uint4 pk;
      pk.x = packh2(f0.x, f0.y); pk.y = packh2(f0.z, f0.w);
      pk.z = packh2(f1.x, f1.y); pk.w = packh2(f1.z, f1.w);
      *(uint4*)(dst + i*8) = pk;
    }
  }
  __syncthreads();

  fx4 acc[2][4];
  #pragma unroll
  for (int mt = 0; mt < 2; ++mt)
    #pragma unroll
    for (int j = 0; j < 4; ++j) acc[mt][j] = fx4{0,0,0,0};

  const u16* As0 = &Smem[l15*ASTRIDE + (quad << 3)];
  const u16* As1 = As0 + 16*ASTRIDE;
  asm volatile("s_waitcnt vmcnt(0)" ::: "memory");
  __builtin_amdgcn_sched_barrier(0);
  #pragma unroll
  for (int s = 0; s < 8; ++s){
    h8 af0 = *(const h8*)(As0 + s*32);
    h8 af1 = *(const h8*)(As1 + s*32);
    #pragma unroll
    for (int j = 0; j < 4; ++j){
      h8 bf = as_h8(breg[s*4+j]);
      acc[0][j] = __builtin_amdgcn_mfma_f32_16x16x32_f16(af0, bf, acc[0][j], 0, 0, 0);
      acc[1][j] = __builtin_amdgcn_mfma_f32_16x16x32_f16(af1, bf, acc[1][j], 0, 0, 0);
    }
  }

  // epilogue: transpose through LDS (all 4 waves, distinct cols)
  __syncthreads();
  #pragma unroll
  for (int j = 0; j < 4; ++j){
    const int n = wave*64 + j*16 + l15;
    const float bias = bq[m0*256 + n] * SCALE_Q;
    #pragma unroll
    for (int mt = 0; mt < 2; ++mt)
      #pragma unroll
      for (int reg = 0; reg < 4; ++reg){
        const int row = mt*16 + quad*4 + reg;
        Smem[row*ASTRIDE + n] = f2h_bits(acc[mt][j][reg] + bias);
      }
  }
  __syncthreads();
  {
    const int row_ = tid >> 3, hsel = tid & 7;
    const int r_g = tile*32 + row_;
    const int xy = r_g / 49, ef = r_g - xy*49;
    u16* dst = qbuf + (((size_t)(b*64 + xy)*8 + hsel)*49 + ef)*32;
    const u16* srcl = &Smem[row_*ASTRIDE + hsel*32];
    *(uint4*)(dst)      = *(const uint4*)(srcl);
    *(uint4*)(dst + 8)  = *(const uint4*)(srcl + 8);
    *(uint4*)(dst + 16) = *(const uint4*)(srcl + 16);
    *(uint4*)(dst + 24) = *(const uint4*)(srcl + 24);
  }
}

// ---------------------------------------------------------------------------
// K3 v6: attention — ONE WAVE per (bloc,xy,h), MFMA-based (unchanged).
// ---------------------------------------------------------------------------
__global__ __launch_bounds__(64) void attn_kernel(
    const u16* __restrict__ qbuf, const u16* __restrict__ kw,
    const u16* __restrict__ vm,   const float* __restrict__ post,
    u16* __restrict__ aout, int b0)
{
  __shared__ u32 Ks[64*16];     // K rows [ke][p] (ke 49..63 zeroed once)   4KB
  __shared__ u16 VT[32*64];     // V^T [p][ke], ke-chunk XOR-swizzled       4KB
  __shared__ u16 PQ[64*64];     // Q staging [qi][32] -> P^T [qi][ke] swz   8KB
  __shared__ float poss[169];

  const int bloc  = blockIdx.x >> 9;
  const int local = blockIdx.x & 511;      // xy*8+h
  const int h = local & 7, xy = local >> 3;
  const int bxy = (b0 + bloc)*64 + xy;
  const int lane = threadIdx.x;            // 0..63
  const int quad = lane >> 4, l15 = lane & 15;

  for (int i = lane; i < 169; i += 64) poss[i] = post[i*8 + h];
  for (int i = lane; i < 240; i += 64) Ks[784 + i] = 0;     // K pad rows
  for (int i = lane; i < 512; i += 64){                     // VT pad (ke 48..63)
    const int p = i >> 4, ke = 48 + (i & 15);
    VT[p*64 + ((((ke >> 3) ^ (p & 7)) & 7) << 3) + (ke & 7)] = 0;
  }
  { const u16* qsrc = qbuf + (size_t)(bxy*8 + h)*1568;      // Q rows -> PQ[qi][32]
    for (int i = lane; i < 196; i += 64)
      *(uint4*)&PQ[(i >> 2)*32 + (i & 3)*8] = *(const uint4*)(qsrc + (size_t)i*8);
    const uint4 z4 = make_uint4(0,0,0,0);
    for (int i = lane; i < 60; i += 64)                     // rows 49..63 zero
      *(uint4*)&PQ[1568 + i*8] = z4;
  }
  __syncthreads();

  // Q B-frags (persist across all z)
  h8 qf[4];
  #pragma unroll
  for (int nt = 0; nt < 4; ++nt)
    qf[nt] = *(const h8*)&PQ[(nt*16 + l15)*32 + quad*8];

  // bias C-in frags (persist): element (ke = mt*16+quad*4+reg, qi = nt*16+l15)
  fx4 bias[4][4];
  { int qa[4], qb[4];
    #pragma unroll
    for (int nt = 0; nt < 4; ++nt){
      const int qi = nt*16 + l15; qa[nt] = qi/7; qb[nt] = qi - qa[nt]*7;
    }
    #pragma unroll
    for (int mt = 0; mt < 4; ++mt)
      #pragma unroll
      for (int reg = 0; reg < 4; ++reg){
        const int ke = mt*16 + quad*4 + reg;
        const int ka = ke/7, kb = ke - ka*7;
        #pragma unroll
        for (int nt = 0; nt < 4; ++nt){
          const int qi = nt*16 + l15;
          float bv;
          if (ke > 48)      bv = -1e30f;
          else if (qi > 48) bv = 0.f;
          else              bv = poss[(qa[nt] - ka + 6)*13 + (qb[nt] - kb + 6)];
          bias[mt][nt][reg] = bv;
        }
      }
  }

  const size_t kvbase = ((size_t)(bloc*64 + xy)*8 + h)*6;
  float mprev[4], lsum[4];
  fx4 Oacc[2][4];
  #pragma unroll
  for (int nt = 0; nt < 4; ++nt){
    mprev[nt] = -1e30f; lsum[nt] = 0.f;
    Oacc[0][nt] = fx4{0,0,0,0}; Oacc[1][nt] = fx4{0,0,0,0};
  }

  for (int z = 0; z < 6; ++z){
    __syncthreads();   // previous phase's LDS reads complete
    { const uint4* ksrc = (const uint4*)((const u32*)kw + (kvbase + z)*784);
      for (int i = lane; i < 196; i += 64) ((uint4*)Ks)[i] = ksrc[i];
      const uint4* vsrc = (const uint4*)((const u32*)vm + (kvbase + z)*784);
      for (int i = lane; i < 196; i += 64){
        uint4 v4 = vsrc[i];
        const int ef = i >> 2, pb = (i & 3)*8;
        const int c0 = ef >> 3;
        u16* vt = VT + (ef & 7);
        vt[(pb+0)*64 + ((c0 ^ 0) << 3)] = (u16)(v4.x & 0xFFFFu);
        vt[(pb+1)*64 + ((c0 ^ 1) << 3)] = (u16)(v4.x >> 16);
        vt[(pb+2)*64 + ((c0 ^ 2) << 3)] = (u16)(v4.y & 0xFFFFu);
        vt[(pb+3)*64 + ((c0 ^ 3) << 3)] = (u16)(v4.y >> 16);
        vt[(pb+4)*64 + ((c0 ^ 4) << 3)] = (u16)(v4.z & 0xFFFFu);
        vt[(pb+5)*64 + ((c0 ^ 5) << 3)] = (u16)(v4.z >> 16);
        vt[(pb+6)*64 + ((c0 ^ 6) << 3)] = (u16)(v4.w & 0xFFFFu);
        vt[(pb+7)*64 + ((c0 ^ 7) << 3)] = (u16)(v4.w >> 16);
      } }
    __syncthreads();

    // ---- S^T = K·Q^T + bias (16 MFMA) ----
    h8 kf[4];
    #pragma unroll
    for (int mt = 0; mt < 4; ++mt)
      kf[mt] = *(const h8*)((const u16*)Ks + (mt*16 + l15)*32 + quad*8);
    fx4 S[4][4];
    #pragma unroll
    for (int mt = 0; mt < 4; ++mt)
      #pragma unroll
      for (int nt = 0; nt < 4; ++nt)
        S[mt][nt] = __builtin_amdgcn_mfma_f32_16x16x32_f16(kf[mt], qf[nt], bias[mt][nt], 0, 0, 0);

    // ---- online softmax per qi-column group nt ----
    #pragma unroll
    for (int nt = 0; nt < 4; ++nt){
      float cm = S[0][nt][0];
      #pragma unroll
      for (int mt = 0; mt < 4; ++mt)
        #pragma unroll
        for (int r = 0; r < 4; ++r) cm = fmaxf(cm, S[mt][nt][r]);
      cm = fmaxf(cm, __shfl_xor(cm, 16));
      cm = fmaxf(cm, __shfl_xor(cm, 32));
      const float mnew = fmaxf(mprev[nt], cm);
      const float alpha = __expf(mprev[nt] - mnew);
      mprev[nt] = mnew;
      float sum = 0.f;
      #pragma unroll
      for (int mt = 0; mt < 4; ++mt)
        #pragma unroll
        for (int r = 0; r < 4; ++r){
          float e = __expf(S[mt][nt][r] - mnew); S[mt][nt][r] = e; sum += e;
        }
      sum += __shfl_xor(sum, 16);
      sum += __shfl_xor(sum, 32);
      lsum[nt] = lsum[nt]*alpha + sum;
      #pragma unroll
      for (int r = 0; r < 4; ++r){ Oacc[0][nt][r] *= alpha; Oacc[1][nt][r] *= alpha; }
    }

    // ---- pack P^T into PQ (swizzled): ke chunk = mt*2 + (quad>>1) ----
    #pragma unroll
    for (int nt = 0; nt < 4; ++nt){
      const int qi = nt*16 + l15;
      u16* prow = &PQ[qi*64 + ((quad & 1) << 2)];
      #pragma unroll
      for (int mt = 0; mt < 4; ++mt){
        const int chk = (mt*2 + (quad >> 1)) ^ (l15 & 7);
        uint2 w;
        w.x = packh2(S[mt][nt][0], S[mt][nt][1]);
        w.y = packh2(S[mt][nt][2], S[mt][nt][3]);
        *(uint2*)(prow + (chk << 3)) = w;
      }
    }
    __syncthreads();

    // ---- O^T += V^T · P^T (16 MFMA over 2 k-steps) ----
    #pragma unroll
    for (int ks = 0; ks < 2; ++ks){
      h8 vf[2];
      #pragma unroll
      for (int m2 = 0; m2 < 2; ++m2)
        vf[m2] = *(const h8*)&VT[(m2*16 + l15)*64 + (((ks*4 + quad) ^ (l15 & 7)) << 3)];
      #pragma unroll
      for (int nt = 0; nt < 4; ++nt){
        h8 pf = *(const h8*)&PQ[(nt*16 + l15)*64 + (((ks*4 + quad) ^ (l15 & 7)) << 3)];
        Oacc[0][nt] = __builtin_amdgcn_mfma_f32_16x16x32_f16(vf[0], pf, Oacc[0][nt], 0, 0, 0);
        Oacc[1][nt] = __builtin_amdgcn_mfma_f32_16x16x32_f16(vf[1], pf, Oacc[1][nt], 0, 0, 0);
      }
    }
  }

  // ---- normalize + store via LDS roundtrip ----
  __syncthreads();
  #pragma unroll
  for (int nt = 0; nt < 4; ++nt){
    const int qi = nt*16 + l15;
    if (qi < 49){
      const float inv = 1.f / lsum[nt];
      #pragma unroll
      for (int m2 = 0; m2 < 2; ++m2){
        uint2 w;
        w.x = packh2(Oacc[m2][nt][0]*inv, Oacc[m2][nt][1]*inv);
        w.y = packh2(Oacc[m2][nt][2]*inv, Oacc[m2][nt][3]*inv);
        *(uint2*)&PQ[qi*32 + m2*16 + quad*4] = w;
      }
    }
  }
  __syncthreads();
  { u16* obase = aout + (size_t)bxy*12544 + h*32;
    for (int i = lane; i < 196; i += 64){
      const int r = i >> 2, c = (i & 3)*8;
      *(uint4*)(obase + (size_t)r*256 + c) = *(const uint4*)&PQ[r*32 + c];
    }
  }
}

// ---------------------------------------------------------------------------
// K4 v2: final projection — MFMA, kwv template. A = aout f16 (staged raw),
// B = Waf[m0] f16 k-step-major, bias ba. fp32 output via LDS float
// transpose -> coalesced float4 stores. BM=32, BN=256, grid = 4*98.
// ---------------------------------------------------------------------------
__global__ __launch_bounds__(256, 2) void gemm_op(
    const u16* __restrict__ aout, const int* __restrict__ mode,
    const u16* __restrict__ Waf, const float* __restrict__ ba,
    float* __restrict__ outp)
{
  __shared__ float Smf[32*260];          // 33.3 KB; low half doubles as u16 A-tile
  u16* Smem = (u16*)Smf;
  const int rowT = blockIdx.x;       // b*98 + tile
  const int b = rowT / 98, tile = rowT % 98;
  const int m0 = mode[b*6];
  const u16* Abase = aout + ((size_t)b*3136 + (size_t)tile*32)*256;
  const int tid = threadIdx.x;
  const int wave = tid >> 6, lane = tid & 63;
  const int quad = lane >> 4, l15 = lane & 15;

  const u16* Bp = Waf + (size_t)m0*65536 + (size_t)((wave << 6) + l15)*32 + (quad << 3);
  uint4 breg[32];
  #pragma unroll
  for (int s = 0; s < 8; ++s)
    #pragma unroll
    for (int j = 0; j < 4; ++j){
      const u16* ap = Bp + (size_t)s*8192 + j*512;
      asm volatile("global_load_dwordx4 %0, %1, off" : "=v"(breg[s*4+j]) : "v"(ap));
    }

  // A-stage: raw f16 copy
  {
    const int r = tid >> 3, cseg = (tid & 7)*32;
    const u16* src = Abase + (size_t)r*256 + cseg;
    u16* dst = &Smem[r*ASTRIDE + cseg];
    #pragma unroll
    for (int i = 0; i < 4; ++i)
      *(uint4*)(dst + i*8) = *(const uint4*)(src + i*8);
  }
  __syncthreads();

  fx4 acc[2][4];
  #pragma unroll
  for (int mt = 0; mt < 2; ++mt)
    #pragma unroll
    for (int j = 0; j < 4; ++j) acc[mt][j] = fx4{0,0,0,0};

  const u16* As0 = &Smem[l15*ASTRIDE + (quad << 3)];
  const u16* As1 = As0 + 16*ASTRIDE;
  asm volatile("s_waitcnt vmcnt(0)" ::: "memory");
  __builtin_amdgcn_sched_barrier(0);
  #pragma unroll
  for (int s = 0; s < 8; ++s){
    h8 af0 = *(const h8*)(As0 + s*32);
    h8 af1 = *(const h8*)(As1 + s*32);
    #pragma unroll
    for (int j = 0; j < 4; ++j){
      h8 bf = as_h8(breg[s*4+j]);
      acc[0][j] = __builtin_amdgcn_mfma_f32_16x16x32_f16(af0, bf, acc[0][j], 0, 0, 0);
      acc[1][j] = __builtin_amdgcn_mfma_f32_16x16x32_f16(af1, bf, acc[1][j], 0, 0, 0);
    }
  }

  // epilogue: float transpose through LDS, then coalesced stores
  __syncthreads();
  #pragma unroll
  for (int j = 0; j < 4; ++j){
    const int n = wave*64 + j*16 + l15;
    const float bias = ba[m0*256 + n];
    #pragma unroll
    for (int mt = 0; mt < 2; ++mt)
      #pragma unroll
      for (int reg = 0; reg < 4; ++reg){
        const int row = mt*16 + quad*4 + reg;
        Smf[row*260 + n] = acc[mt][j][reg] + bias;
      }
  }
  __syncthreads();
  {
    const int row_ = tid >> 3, seg = (tid & 7)*32;
    const int rowg = b*3136 + tile*32 + row_;
    float* dst = outp + (size_t)rowg*256 + seg;
    const float* srcl = &Smf[row_*260 + seg];
    #pragma unroll
    for (int i = 0; i < 8; ++i)
      *(float4*)(dst + i*4) = *(const float4*)(srcl + i*4);
  }
}

// ---------------------------------------------------------------------------
extern "C" void kernel_launch(void* const* d_in, const int* in_sizes, int n_in,
                              void* d_out, int out_size, void* d_ws, size_t ws_size,
                              hipStream_t stream)
{
  float* outp = (float*)d_out;
  const int FLAG_GRID = (out_size + 255)/256;

  if (n_in != 13) { flag_fill<<<FLAG_GRID,256,0,stream>>>(outp, out_size, 2000.f); return; }
  if (in_sizes[0] != 4*6*64*49*256) { flag_fill<<<FLAG_GRID,256,0,stream>>>(outp, out_size, 3000.f); return; }
  if (in_sizes[1] != 24) { flag_fill<<<FLAG_GRID,256,0,stream>>>(outp, out_size, 4000.f); return; }

  const size_t SZ_WFT  = (size_t)4*512*256*2;               //  1 MB (f16)
  const size_t SZ_BFF  = (size_t)4*512*sizeof(float);       //  8 KB
  const size_t SZ_WQF  = (size_t)2*256*256*2;               //  256 KB (f16)
  const size_t SZ_WAF  = (size_t)2*256*256*2;               //  256 KB (f16)
  const size_t SZ_Q    = (size_t)12544*256*2;               //  6.4 MB (f16)
  const size_t SZ_AOUT = (size_t)12544*256*2;               //  6.4 MB (f16)
  const size_t SZ_KW1  = (size_t)64*8*6*49*32*2;            //  9.63 MB / batch
  const size_t SZ_VM1  = SZ_KW1;                            //  unified layout
  const size_t FIXED   = SZ_WFT + SZ_BFF + SZ_WQF + SZ_WAF + SZ_Q + SZ_AOUT;
  if (ws_size < FIXED + SZ_KW1 + SZ_VM1) { flag_fill<<<FLAG_GRID,256,0,stream>>>(outp, out_size, 1000.f); return; }

  int nb = 1;
  if (ws_size >= FIXED + 4*(SZ_KW1 + SZ_VM1)) nb = 4;
  else if (ws_size >= FIXED + 2*(SZ_KW1 + SZ_VM1)) nb = 2;

  const float* x    = (const float*)d_in[0];
  const int*   mode = (const int*)d_in[1];
  const float* Wq   = (const float*)d_in[2];
  const float* bq   = (const float*)d_in[3];
  const float* Wk   = (const float*)d_in[4];
  const float* bk   = (const float*)d_in[5];
  const float* Wv   = (const float*)d_in[6];
  const float* bv   = (const float*)d_in[7];
  const float* Wa   = (const float*)d_in[8];
  const float* ba   = (const float*)d_in[9];
  const float* Ratt = (const float*)d_in[10];
  const float* Rmsg = (const float*)d_in[11];
  const float* post = (const float*)d_in[12];

  char* w = (char*)d_ws;
  u16* Wft   = (u16*)w;   w += SZ_WFT;
  float* bff = (float*)w; w += SZ_BFF;
  u16* Wqf   = (u16*)w;   w += SZ_WQF;
  u16* Waf   = (u16*)w;   w += SZ_WAF;
  u16* qbuf  = (u16*)w;   w += SZ_Q;
  u16* aout  = (u16*)w;   w += SZ_AOUT;
  u16* kwbuf = (u16*)w;   w += (size_t)nb*SZ_KW1;
  u16* vmbuf = (u16*)w;   w += (size_t)nb*SZ_VM1;

  fuse_w<<<dim3(4,256), 512, 0, stream>>>(Wk, Wv, Ratt, Rmsg, Wft);
  fuse_b<<<4, 512, 0, stream>>>(bk, bv, Ratt, Rmsg, bff);
  fuse_qo<<<dim3(2,256), 512, 0, stream>>>(Wq, Wa, Wqf, Waf);
  gemm_qp<<<392, 256, 0, stream>>>(x, mode, Wqf, bq, qbuf);
  for (int b0 = 0; b0 < 4; b0 += nb) {
    gemm_kwv<<<nb*588, 256, 0, stream>>>(x, mode, Wft, bff, kwbuf, vmbuf, b0);
    attn_kernel<<<nb*512, 64, 0, stream>>>(qbuf, kwbuf, vmbuf, post, aout, b0);
  }
  gemm_op<<<392, 256, 0, stream>>>(aout, mode, Waf, ba, outp);
}

// Round 6
// 271.388 us; speedup vs baseline: 1.4741x; 1.0378x over previous
//
#include <hip/hip_runtime.h>

typedef unsigned short u16;
typedef unsigned int   u32;
typedef _Float16 f16;
typedef _Float16 h2  __attribute__((ext_vector_type(2)));
typedef _Float16 h8  __attribute__((ext_vector_type(8)));
typedef float    fx4 __attribute__((ext_vector_type(4)));

// ---- problem constants ----
// B=4 L=6 X=Y=8 -> 256 sites, W=49 window, D=256, h=8, dh=32
#define SCALE_Q 0.17677669529663687f

__device__ __forceinline__ u16 f2h_bits(float f){
  union{ f16 h; u16 u; } v; v.h = (f16)f; return v.u;
}
__device__ __forceinline__ u32 packh2(float a, float b){
  union{ h2 h; u32 u; } v; v.h = h2{(f16)a, (f16)b}; return v.u;
}
__device__ __forceinline__ h2 as_h2(u32 x){
  union{ u32 u; h2 h; } v; v.u = x; return v.h;
}
__device__ __forceinline__ h8 as_h8(uint4 u){
  union{ uint4 u; h8 h; } v; v.u = u; return v.h;
}

// diagnostic fill (fp32): encodes which runtime assumption failed
__global__ void flag_fill(float* out, int n, float v){
  int i = blockIdx.x*256 + threadIdx.x;
  if (i < n) out[i] = v;
}

// ---------------------------------------------------------------------------
// K0 (merged): fuse_w + fuse_b + fuse_qo in ONE launch.
//  blocks 0..1023   : Wft[rel][k/32][n][k&31]  (relation-fused K/V weights)
//  blocks 1024..1027: bff (fused biases)
//  blocks 1028..1539: Wqf (SCALE_Q folded) / Waf  k-step-major casts
// ---------------------------------------------------------------------------
__global__ __launch_bounds__(512) void fuse_all(
    const float* __restrict__ Wk, const float* __restrict__ Wv,
    const float* __restrict__ Ratt, const float* __restrict__ Rmsg,
    const float* __restrict__ Wq, const float* __restrict__ Wa,
    const float* __restrict__ bk, const float* __restrict__ bv,
    u16* __restrict__ Wft, float* __restrict__ bff,
    u16* __restrict__ Wqf, u16* __restrict__ Waf)
{
  const int blk = blockIdx.x;
  const int n = threadIdx.x;
  if (blk < 1024){
    const int rel = blk >> 8, d = blk & 255, ml = rel & 1;
    float acc = 0.f;
    if (n < 256) {
      const int h = n >> 5, p = n & 31;
      const float* wcol = Wk + (size_t)ml*65536 + (size_t)(h*32)*256 + d;
      const float* rrow = Ratt + ((size_t)(rel*8 + h)*32 + p)*32;
      #pragma unroll
      for (int q = 0; q < 32; ++q) acc += wcol[q*256] * rrow[q];
    } else {
      const int n2 = n - 256, h = n2 >> 5, qq = n2 & 31;
      const float* wcol = Wv + (size_t)ml*65536 + (size_t)(h*32)*256 + d;
      const float* rcol = Rmsg + ((size_t)(rel*8 + h)*32)*32 + qq;
      #pragma unroll
      for (int p2 = 0; p2 < 32; ++p2) acc += wcol[p2*256] * rcol[p2*32];
    }
    Wft[(size_t)rel*131072 + (size_t)(d >> 5)*16384 + (size_t)n*32 + (d & 31)] = f2h_bits(acc);
  } else if (blk < 1028){
    const int rel = blk - 1024, ml = rel & 1;
    float acc = 0.f;
    if (n < 256) {
      const int h = n >> 5, p = n & 31;
      const float* rrow = Ratt + ((size_t)(rel*8 + h)*32 + p)*32;
      #pragma unroll
      for (int q = 0; q < 32; ++q) acc += bk[ml*256 + h*32 + q] * rrow[q];
    } else {
      const int n2 = n - 256, h = n2 >> 5, qq = n2 & 31;
      const float* rcol = Rmsg + ((size_t)(rel*8 + h)*32)*32 + qq;
      #pragma unroll
      for (int p2 = 0; p2 < 32; ++p2) acc += bv[ml*256 + h*32 + p2] * rcol[p2*32];
    }
    bff[rel*512 + n] = acc;
  } else {
    const int bb = blk - 1028;
    const int t = bb >> 8, d = bb & 255;
    if (n < 256){
      float v = Wq[(size_t)t*65536 + (size_t)n*256 + d] * SCALE_Q;
      Wqf[(size_t)t*65536 + (size_t)(d >> 5)*8192 + (size_t)n*32 + (d & 31)] = f2h_bits(v);
    } else {
      const int e = n - 256;
      float v = Wa[(size_t)t*65536 + (size_t)e*256 + d];
      Waf[(size_t)t*65536 + (size_t)(d >> 5)*8192 + (size_t)e*32 + (d & 31)] = f2h_bits(v);
    }
  }
}

// ---------------------------------------------------------------------------
// K1 v7b: fused kw / v_msg projection GEMM — MFMA (16x16x32 f16).
// BM=64, BN=512, 512 threads (8 waves; wave owns 64 n-cols), grid = nb*294.
// WHY: BM=32 moved 602 MB of Wft B-fragments through L2/L3 per dispatch
// (256KB x 2352 blocks) -> cache-BW bound. BM=64 halves B traffic to 301 MB
// with acc still 64 regs/lane (4mt x 4j).
//  * A-stage wave-linear coalesced (1KB/instr contiguous).
//  * B: 3-slot rotating pinned prefetch, counted vmcnt (never a mid-loop
//    full drain); prologue slots drain under the A-stage barrier.
//  * __launch_bounds__(512) WITHOUT a min-wave arg: k-loop live set is
//    acc(64)+breg(48)+af(16)+addr ~ 140 VGPR. A (512,2) cap of 128 forces
//    spills around asm-pinned regs AND scratch ops inside the k-loop would
//    invalidate the hand-counted vmcnt (scratch increments vmcnt).
//  * Epilogue: LDS transpose (verified layout), two halves kw/vm.
// Outputs kw/vm[bloc][xy][h][l][ef][p] (f16) — unchanged.
// ---------------------------------------------------------------------------
#define ASTRIDE 264   // u16 elements per LDS row (16B-aligned, conflict-light)

__global__ __launch_bounds__(512) void gemm_kwv(
    const float* __restrict__ x, const int* __restrict__ mode,
    const u16* __restrict__ Wft, const float* __restrict__ bff,
    u16* __restrict__ kw, u16* __restrict__ vm, int b0)
{
  __shared__ u16 Smem[64*ASTRIDE];   // 33.8 KB: A-tile, then epilogue buffer
  const int rowT  = blockIdx.x;              // bloc*294 + l*49 + tile
  const int bloc = rowT / 294;
  const int rem  = rowT % 294;
  const int l = rem / 49, tile = rem % 49;
  const int b = b0 + bloc;
  const int rel = mode[b*6]*2 + mode[b*6 + l];
  const float* Abase = x + ((size_t)(b*6 + l)*3136 + (size_t)tile*64)*256;
  const int tid  = threadIdx.x;
  const int wave = tid >> 6, lane = tid & 63;
  const int quad = lane >> 4, l15 = lane & 15;

  // per-lane B base in k-step-major layout [rel][s][n][32]; wave owns 64 cols
  const u16* Bp = Wft + (size_t)rel*131072 + (size_t)((wave << 6) + l15)*32 + (quad << 3);

  // ---- prologue: pin k-steps 0..2 into 3 rotating slots (12 loads) ----
  uint4 breg[3][4];
  #pragma unroll
  for (int s = 0; s < 3; ++s)
    #pragma unroll
    for (int j = 0; j < 4; ++j){
      const u16* ap = Bp + (size_t)s*16384 + j*512;
      asm volatile("global_load_dwordx4 %0, %1, off" : "=v"(breg[s][j]) : "v"(ap));
    }

  // ---- stage A (64x256 fp32 -> f16 LDS), wave-linear coalesced ----
  #pragma unroll
  for (int i = 0; i < 8; ++i){
    float4 f = *(const float4*)(Abase + (size_t)i*2048 + tid*4);
    const int row = i*8 + (tid >> 6), col = (tid & 63)*4;
    uint2 pk; pk.x = packh2(f.x, f.y); pk.y = packh2(f.z, f.w);
    *(uint2*)&Smem[row*ASTRIDE + col] = pk;
  }
  __syncthreads();   // compiler drains vmcnt before s_barrier: slots 0..2 ready

  fx4 acc[4][4];
  #pragma unroll
  for (int mt = 0; mt < 4; ++mt)
    #pragma unroll
    for (int j = 0; j < 4; ++j) acc[mt][j] = fx4{0,0,0,0};

  const u16* As = &Smem[l15*ASTRIDE + (quad << 3)];

  // ---- k-loop: 8 steps, 3-slot rotation, counted vmcnt ----
  // outstanding at top of step s: refills issued at s-3,s-2,s-1 (4 each).
  #pragma unroll
  for (int s = 0; s < 8; ++s){
    if (s >= 3 && s <= 5)      { asm volatile("s_waitcnt vmcnt(8)" ::: "memory"); }
    else if (s == 6)           { asm volatile("s_waitcnt vmcnt(4)" ::: "memory"); }
    else if (s == 7)           { asm volatile("s_waitcnt vmcnt(0)" ::: "memory"); }
    __builtin_amdgcn_sched_barrier(0);
    h8 af[4];
    #pragma unroll
    for (int mt = 0; mt < 4; ++mt)
      af[mt] = *(const h8*)(As + (mt*16)*ASTRIDE + s*32);
    const int slot = s % 3;
    #pragma unroll
    for (int j = 0; j < 4; ++j){
      h8 bf = as_h8(breg[slot][j]);
      #pragma unroll
      for (int mt = 0; mt < 4; ++mt)
        acc[mt][j] = __builtin_amdgcn_mfma_f32_16x16x32_f16(af[mt], bf, acc[mt][j], 0, 0, 0);
    }
    if (s < 5){
      #pragma unroll
      for (int j = 0; j < 4; ++j){
        const u16* ap = Bp + (size_t)(s + 3)*16384 + j*512;
        asm volatile("global_load_dwordx4 %0, %1, off" : "=v"(breg[slot][j]) : "v"(ap));
      }
    }
  }

  // ---- epilogue: LDS transpose, two halves (kw = waves 0-3 / vm = 4-7) ----
  const int row_ = tid >> 3;        // 0..63
  const int hsel = tid & 7;         // 0..7
  const int r_g  = tile*64 + row_;  // 0..3135
  const int xy   = r_g / 49, ef = r_g - xy*49;

  #pragma unroll
  for (int half = 0; half < 2; ++half){
    __syncthreads();   // protect Smem (A-tile reads / previous half's reads)
    if ((wave >> 2) == half){
      #pragma unroll
      for (int j = 0; j < 4; ++j){
        const int n   = wave*64 + j*16 + l15;   // 0..511
        const int col = n & 255;
        const float bias = bff[rel*512 + n];
        #pragma unroll
        for (int mt = 0; mt < 4; ++mt){
          #pragma unroll
          for (int reg = 0; reg < 4; ++reg){
            const int row = mt*16 + quad*4 + reg;
            Smem[row*ASTRIDE + col] = f2h_bits(acc[mt][j][reg] + bias);
          }
        }
      }
    }
    __syncthreads();
    u16* dbuf = half ? vm : kw;
    u16* dst  = dbuf + ((((size_t)(bloc*64 + xy)*8 + hsel)*6 + l)*49 + ef)*32;
    const u16* srcl = &Smem[row_*ASTRIDE + hsel*32];
    *(uint4*)(dst)      = *(const uint4*)(srcl);
    *(uint4*)(dst + 8)  = *(const uint4*)(srcl + 8);
    *(uint4*)(dst + 16) = *(const uint4*)(srcl + 16);
    *(uint4*)(dst + 24) = *(const uint4*)(srcl + 24);
  }
}

// ---------------------------------------------------------------------------
// K2 v2: q projection (l=0 only) — MFMA. BM=32, BN=256, grid = 4*98.
// ---------------------------------------------------------------------------
__global__ __launch_bounds__(256, 2) void gemm_qp(
    const float* __restrict__ x, const int* __restrict__ mode,
    const u16* __restrict__ Wqf, const float* __restrict__ bq,
    u16* __restrict__ qbuf)
{
  __shared__ u16 Smem[32*ASTRIDE];
  const int rowT = blockIdx.x;       // b*98 + tile
  const int b = rowT / 98, tile = rowT % 98;
  const int m0 = mode[b*6];
  const float* Abase = x + ((size_t)(b*6)*3136 + (size_t)tile*32)*256;
  const int tid = threadIdx.x;
  const int wave = tid >> 6, lane = tid & 63;
  const int quad = lane >> 4, l15 = lane & 15;

  const u16* Bp = Wqf + (size_t)m0*65536 + (size_t)((wave << 6) + l15)*32 + (quad << 3);
  uint4 breg[32];
  #pragma unroll
  for (int s = 0; s < 8; ++s)
    #pragma unroll
    for (int j = 0; j < 4; ++j){
      const u16* ap = Bp + (size_t)s*8192 + j*512;
      asm volatile("global_load_dwordx4 %0, %1, off" : "=v"(breg[s*4+j]) : "v"(ap));
    }

  {
    const int r = tid >> 3, cseg = (tid & 7)*32;
    const float* src = Abase + (size_t)r*256 + cseg;
    u16* dst = &Smem[r*ASTRIDE + cseg];
    #pragma unroll
    for (int i = 0; i < 4; ++i){
      float4 f0 = *(const float4*)(src + i*8);
      float4 f1 = *(const float4*)(src + i*8 + 4);
      uint4 pk;
      pk.x = packh2(f0.x, f0.y); pk.y = packh2(f0.z, f0.w);
      pk.z = packh2(f1.x, f1.y); pk.w = packh2(f1.z, f1.w);
      *(uint4*)(dst + i*8) = pk;
    }
  }
  __syncthreads();

  fx4 acc[2][4];
  #pragma unroll
  for (int mt = 0; mt < 2; ++mt)
    #pragma unroll
    for (int j = 0; j < 4; ++j) acc[mt][j] = fx4{0,0,0,0};

  const u16* As0 = &Smem[l15*ASTRIDE + (quad << 3)];
  const u16* As1 = As0 + 16*ASTRIDE;
  asm volatile("s_waitcnt vmcnt(0)" ::: "memory");
  __builtin_amdgcn_sched_barrier(0);
  #pragma unroll
  for (int s = 0; s < 8; ++s){
    h8 af0 = *(const h8*)(As0 + s*32);
    h8 af1 = *(const h8*)(As1 + s*32);
    #pragma unroll
    for (int j = 0; j < 4; ++j){
      h8 bf = as_h8(breg[s*4+j]);
      acc[0][j] = __builtin_amdgcn_mfma_f32_16x16x32_f16(af0, bf, acc[0][j], 0, 0, 0);
      acc[1][j] = __builtin_amdgcn_mfma_f32_16x16x32_f16(af1, bf, acc[1][j], 0, 0, 0);
    }
  }

  __syncthreads();
  #pragma unroll
  for (int j = 0; j < 4; ++j){
    const int n = wave*64 + j*16 + l15;
    const float bias = bq[m0*256 + n] * SCALE_Q;
    #pragma unroll
    for (int mt = 0; mt < 2; ++mt)
      #pragma unroll
      for (int reg = 0; reg < 4; ++reg){
        const int row = mt*16 + quad*4 + reg;
        Smem[row*ASTRIDE + n] = f2h_bits(acc[mt][j][reg] + bias);
      }
  }
  __syncthreads();
  {
    const int row_ = tid >> 3, hsel = tid & 7;
    const int r_g = tile*32 + row_;
    const int xy = r_g / 49, ef = r_g - xy*49;
    u16* dst = qbuf + (((size_t)(b*64 + xy)*8 + hsel)*49 + ef)*32;
    const u16* srcl = &Smem[row_*ASTRIDE + hsel*32];
    *(uint4*)(dst)      = *(const uint4*)(srcl);
    *(uint4*)(dst + 8)  = *(const uint4*)(srcl + 8);
    *(uint4*)(dst + 16) = *(const uint4*)(srcl + 16);
    *(uint4*)(dst + 24) = *(const uint4*)(srcl + 24);
  }
}

// ---------------------------------------------------------------------------
// K3 v6: attention — ONE WAVE per (bloc,xy,h), MFMA-based (unchanged).
// ---------------------------------------------------------------------------
__global__ __launch_bounds__(64) void attn_kernel(
    const u16* __restrict__ qbuf, const u16* __restrict__ kw,
    const u16* __restrict__ vm,   const float* __restrict__ post,
    u16* __restrict__ aout, int b0)
{
  __shared__ u32 Ks[64*16];     // K rows [ke][p] (ke 49..63 zeroed once)   4KB
  __shared__ u16 VT[32*64];     // V^T [p][ke], ke-chunk XOR-swizzled       4KB
  __shared__ u16 PQ[64*64];     // Q staging [qi][32] -> P^T [qi][ke] swz   8KB
  __shared__ float poss[169];

  const int bloc  = blockIdx.x >> 9;
  const int local = blockIdx.x & 511;      // xy*8+h
  const int h = local & 7, xy = local >> 3;
  const int bxy = (b0 + bloc)*64 + xy;
  const int lane = threadIdx.x;            // 0..63
  const int quad = lane >> 4, l15 = lane & 15;

  for (int i = lane; i < 169; i += 64) poss[i] = post[i*8 + h];
  for (int i = lane; i < 240; i += 64) Ks[784 + i] = 0;     // K pad rows
  for (int i = lane; i < 512; i += 64){                     // VT pad (ke 48..63)
    const int p = i >> 4, ke = 48 + (i & 15);
    VT[p*64 + ((((ke >> 3) ^ (p & 7)) & 7) << 3) + (ke & 7)] = 0;
  }
  { const u16* qsrc = qbuf + (size_t)(bxy*8 + h)*1568;      // Q rows -> PQ[qi][32]
    for (int i = lane; i < 196; i += 64)
      *(uint4*)&PQ[(i >> 2)*32 + (i & 3)*8] = *(const uint4*)(qsrc + (size_t)i*8);
    const uint4 z4 = make_uint4(0,0,0,0);
    for (int i = lane; i < 60; i += 64)                     // rows 49..63 zero
      *(uint4*)&PQ[1568 + i*8] = z4;
  }
  __syncthreads();

  // Q B-frags (persist across all z)
  h8 qf[4];
  #pragma unroll
  for (int nt = 0; nt < 4; ++nt)
    qf[nt] = *(const h8*)&PQ[(nt*16 + l15)*32 + quad*8];

  // bias C-in frags (persist): element (ke = mt*16+quad*4+reg, qi = nt*16+l15)
  fx4 bias[4][4];
  { int qa[4], qb[4];
    #pragma unroll
    for (int nt = 0; nt < 4; ++nt){
      const int qi = nt*16 + l15; qa[nt] = qi/7; qb[nt] = qi - qa[nt]*7;
    }
    #pragma unroll
    for (int mt = 0; mt < 4; ++mt)
      #pragma unroll
      for (int reg = 0; reg < 4; ++reg){
        const int ke = mt*16 + quad*4 + reg;
        const int ka = ke/7, kb = ke - ka*7;
        #pragma unroll
        for (int nt = 0; nt < 4; ++nt){
          const int qi = nt*16 + l15;
          float bv;
          if (ke > 48)      bv = -1e30f;
          else if (qi > 48) bv = 0.f;
          else              bv = poss[(qa[nt] - ka + 6)*13 + (qb[nt] - kb + 6)];
          bias[mt][nt][reg] = bv;
        }
      }
  }

  const size_t kvbase = ((size_t)(bloc*64 + xy)*8 + h)*6;
  float mprev[4], lsum[4];
  fx4 Oacc[2][4];
  #pragma unroll
  for (int nt = 0; nt < 4; ++nt){
    mprev[nt] = -1e30f; lsum[nt] = 0.f;
    Oacc[0][nt] = fx4{0,0,0,0}; Oacc[1][nt] = fx4{0,0,0,0};
  }

  for (int z = 0; z < 6; ++z){
    __syncthreads();   // previous phase's LDS reads complete
    { const uint4* ksrc = (const uint4*)((const u32*)kw + (kvbase + z)*784);
      for (int i = lane; i < 196; i += 64) ((uint4*)Ks)[i] = ksrc[i];
      const uint4* vsrc = (const uint4*)((const u32*)vm + (kvbase + z)*784);
      for (int i = lane; i < 196; i += 64){
        uint4 v4 = vsrc[i];
        const int ef = i >> 2, pb = (i & 3)*8;
        const int c0 = ef >> 3;
        u16* vt = VT + (ef & 7);
        vt[(pb+0)*64 + ((c0 ^ 0) << 3)] = (u16)(v4.x & 0xFFFFu);
        vt[(pb+1)*64 + ((c0 ^ 1) << 3)] = (u16)(v4.x >> 16);
        vt[(pb+2)*64 + ((c0 ^ 2) << 3)] = (u16)(v4.y & 0xFFFFu);
        vt[(pb+3)*64 + ((c0 ^ 3) << 3)] = (u16)(v4.y >> 16);
        vt[(pb+4)*64 + ((c0 ^ 4) << 3)] = (u16)(v4.z & 0xFFFFu);
        vt[(pb+5)*64 + ((c0 ^ 5) << 3)] = (u16)(v4.z >> 16);
        vt[(pb+6)*64 + ((c0 ^ 6) << 3)] = (u16)(v4.w & 0xFFFFu);
        vt[(pb+7)*64 + ((c0 ^ 7) << 3)] = (u16)(v4.w >> 16);
      } }
    __syncthreads();

    // ---- S^T = K·Q^T + bias (16 MFMA) ----
    h8 kf[4];
    #pragma unroll
    for (int mt = 0; mt < 4; ++mt)
      kf[mt] = *(const h8*)((const u16*)Ks + (mt*16 + l15)*32 + quad*8);
    fx4 S[4][4];
    #pragma unroll
    for (int mt = 0; mt < 4; ++mt)
      #pragma unroll
      for (int nt = 0; nt < 4; ++nt)
        S[mt][nt] = __builtin_amdgcn_mfma_f32_16x16x32_f16(kf[mt], qf[nt], bias[mt][nt], 0, 0, 0);

    // ---- online softmax per qi-column group nt ----
    #pragma unroll
    for (int nt = 0; nt < 4; ++nt){
      float cm = S[0][nt][0];
      #pragma unroll
      for (int mt = 0; mt < 4; ++mt)
        #pragma unroll
        for (int r = 0; r < 4; ++r) cm = fmaxf(cm, S[mt][nt][r]);
      cm = fmaxf(cm, __shfl_xor(cm, 16));
      cm = fmaxf(cm, __shfl_xor(cm, 32));
      const float mnew = fmaxf(mprev[nt], cm);
      const float alpha = __expf(mprev[nt] - mnew);
      mprev[nt] = mnew;
      float sum = 0.f;
      #pragma unroll
      for (int mt = 0; mt < 4; ++mt)
        #pragma unroll
        for (int r = 0; r < 4; ++r){
          float e = __expf(S[mt][nt][r] - mnew); S[mt][nt][r] = e; sum += e;
        }
      sum += __shfl_xor(sum, 16);
      sum += __shfl_xor(sum, 32);
      lsum[nt] = lsum[nt]*alpha + sum;
      #pragma unroll
      for (int r = 0; r < 4; ++r){ Oacc[0][nt][r] *= alpha; Oacc[1][nt][r] *= alpha; }
    }

    // ---- pack P^T into PQ (swizzled): ke chunk = mt*2 + (quad>>1) ----
    #pragma unroll
    for (int nt = 0; nt < 4; ++nt){
      const int qi = nt*16 + l15;
      u16* prow = &PQ[qi*64 + ((quad & 1) << 2)];
      #pragma unroll
      for (int mt = 0; mt < 4; ++mt){
        const int chk = (mt*2 + (quad >> 1)) ^ (l15 & 7);
        uint2 w;
        w.x = packh2(S[mt][nt][0], S[mt][nt][1]);
        w.y = packh2(S[mt][nt][2], S[mt][nt][3]);
        *(uint2*)(prow + (chk << 3)) = w;
      }
    }
    __syncthreads();

    // ---- O^T += V^T · P^T (16 MFMA over 2 k-steps) ----
    #pragma unroll
    for (int ks = 0; ks < 2; ++ks){
      h8 vf[2];
      #pragma unroll
      for (int m2 = 0; m2 < 2; ++m2)
        vf[m2] = *(const h8*)&VT[(m2*16 + l15)*64 + (((ks*4 + quad) ^ (l15 & 7)) << 3)];
      #pragma unroll
      for (int nt = 0; nt < 4; ++nt){
        h8 pf = *(const h8*)&PQ[(nt*16 + l15)*64 + (((ks*4 + quad) ^ (l15 & 7)) << 3)];
        Oacc[0][nt] = __builtin_amdgcn_mfma_f32_16x16x32_f16(vf[0], pf, Oacc[0][nt], 0, 0, 0);
        Oacc[1][nt] = __builtin_amdgcn_mfma_f32_16x16x32_f16(vf[1], pf, Oacc[1][nt], 0, 0, 0);
      }
    }
  }

  // ---- normalize + store via LDS roundtrip ----
  __syncthreads();
  #pragma unroll
  for (int nt = 0; nt < 4; ++nt){
    const int qi = nt*16 + l15;
    if (qi < 49){
      const float inv = 1.f / lsum[nt];
      #pragma unroll
      for (int m2 = 0; m2 < 2; ++m2){
        uint2 w;
        w.x = packh2(Oacc[m2][nt][0]*inv, Oacc[m2][nt][1]*inv);
        w.y = packh2(Oacc[m2][nt][2]*inv, Oacc[m2][nt][3]*inv);
        *(uint2*)&PQ[qi*32 + m2*16 + quad*4] = w;
      }
    }
  }
  __syncthreads();
  { u16* obase = aout + (size_t)bxy*12544 + h*32;
    for (int i = lane; i < 196; i += 64){
      const int r = i >> 2, c = (i & 3)*8;
      *(uint4*)(obase + (size_t)r*256 + c) = *(const uint4*)&PQ[r*32 + c];
    }
  }
}

// ---------------------------------------------------------------------------
// K4 v2: final projection — MFMA. A = aout f16, B = Waf[m0] k-step-major,
// bias ba, fp32 out via LDS float transpose. BM=32, BN=256, grid = 4*98.
// ---------------------------------------------------------------------------
__global__ __launch_bounds__(256, 2) void gemm_op(
    const u16* __restrict__ aout, const int* __restrict__ mode,
    const u16* __restrict__ Waf, const float* __restrict__ ba,
    float* __restrict__ outp)
{
  __shared__ float Smf[32*260];          // 33.3 KB; low half doubles as u16 A-tile
  u16* Smem = (u16*)Smf;
  const int rowT = blockIdx.x;       // b*98 + tile
  const int b = rowT / 98, tile = rowT % 98;
  const int m0 = mode[b*6];
  const u16* Abase = aout + ((size_t)b*3136 + (size_t)tile*32)*256;
  const int tid = threadIdx.x;
  const int wave = tid >> 6, lane = tid & 63;
  const int quad = lane >> 4, l15 = lane & 15;

  const u16* Bp = Waf + (size_t)m0*65536 + (size_t)((wave << 6) + l15)*32 + (quad << 3);
  uint4 breg[32];
  #pragma unroll
  for (int s = 0; s < 8; ++s)
    #pragma unroll
    for (int j = 0; j < 4; ++j){
      const u16* ap = Bp + (size_t)s*8192 + j*512;
      asm volatile("global_load_dwordx4 %0, %1, off" : "=v"(breg[s*4+j]) : "v"(ap));
    }

  {
    const int r = tid >> 3, cseg = (tid & 7)*32;
    const u16* src = Abase + (size_t)r*256 + cseg;
    u16* dst = &Smem[r*ASTRIDE + cseg];
    #pragma unroll
    for (int i = 0; i < 4; ++i)
      *(uint4*)(dst + i*8) = *(const uint4*)(src + i*8);
  }
  __syncthreads();

  fx4 acc[2][4];
  #pragma unroll
  for (int mt = 0; mt < 2; ++mt)
    #pragma unroll
    for (int j = 0; j < 4; ++j) acc[mt][j] = fx4{0,0,0,0};

  const u16* As0 = &Smem[l15*ASTRIDE + (quad << 3)];
  const u16* As1 = As0 + 16*ASTRIDE;
  asm volatile("s_waitcnt vmcnt(0)" ::: "memory");
  __builtin_amdgcn_sched_barrier(0);
  #pragma unroll
  for (int s = 0; s < 8; ++s){
    h8 af0 = *(const h8*)(As0 + s*32);
    h8 af1 = *(const h8*)(As1 + s*32);
    #pragma unroll
    for (int j = 0; j < 4; ++j){
      h8 bf = as_h8(breg[s*4+j]);
      acc[0][j] = __builtin_amdgcn_mfma_f32_16x16x32_f16(af0, bf, acc[0][j], 0, 0, 0);
      acc[1][j] = __builtin_amdgcn_mfma_f32_16x16x32_f16(af1, bf, acc[1][j], 0, 0, 0);
    }
  }

  __syncthreads();
  #pragma unroll
  for (int j = 0; j < 4; ++j){
    const int n = wave*64 + j*16 + l15;
    const float bias = ba[m0*256 + n];
    #pragma unroll
    for (int mt = 0; mt < 2; ++mt)
      #pragma unroll
      for (int reg = 0; reg < 4; ++reg){
        const int row = mt*16 + quad*4 + reg;
        Smf[row*260 + n] = acc[mt][j][reg] + bias;
      }
  }
  __syncthreads();
  {
    const int row_ = tid >> 3, seg = (tid & 7)*32;
    const int rowg = b*3136 + tile*32 + row_;
    float* dst = outp + (size_t)rowg*256 + seg;
    const float* srcl = &Smf[row_*260 + seg];
    #pragma unroll
    for (int i = 0; i < 8; ++i)
      *(float4*)(dst + i*4) = *(const float4*)(srcl + i*4);
  }
}

// ---------------------------------------------------------------------------
extern "C" void kernel_launch(void* const* d_in, const int* in_sizes, int n_in,
                              void* d_out, int out_size, void* d_ws, size_t ws_size,
                              hipStream_t stream)
{
  float* outp = (float*)d_out;
  const int FLAG_GRID = (out_size + 255)/256;

  if (n_in != 13) { flag_fill<<<FLAG_GRID,256,0,stream>>>(outp, out_size, 2000.f); return; }
  if (in_sizes[0] != 4*6*64*49*256) { flag_fill<<<FLAG_GRID,256,0,stream>>>(outp, out_size, 3000.f); return; }
  if (in_sizes[1] != 24) { flag_fill<<<FLAG_GRID,256,0,stream>>>(outp, out_size, 4000.f); return; }

  const size_t SZ_WFT  = (size_t)4*512*256*2;               //  1 MB (f16)
  const size_t SZ_BFF  = (size_t)4*512*sizeof(float);       //  8 KB
  const size_t SZ_WQF  = (size_t)2*256*256*2;               //  256 KB (f16)
  const size_t SZ_WAF  = (size_t)2*256*256*2;               //  256 KB (f16)
  const size_t SZ_Q    = (size_t)12544*256*2;               //  6.4 MB (f16)
  const size_t SZ_AOUT = (size_t)12544*256*2;               //  6.4 MB (f16)
  const size_t SZ_KW1  = (size_t)64*8*6*49*32*2;            //  9.63 MB / batch
  const size_t SZ_VM1  = SZ_KW1;                            //  unified layout
  const size_t FIXED   = SZ_WFT + SZ_BFF + SZ_WQF + SZ_WAF + SZ_Q + SZ_AOUT;
  if (ws_size < FIXED + SZ_KW1 + SZ_VM1) { flag_fill<<<FLAG_GRID,256,0,stream>>>(outp, out_size, 1000.f); return; }

  int nb = 1;
  if (ws_size >= FIXED + 4*(SZ_KW1 + SZ_VM1)) nb = 4;
  else if (ws_size >= FIXED + 2*(SZ_KW1 + SZ_VM1)) nb = 2;

  const float* x    = (const float*)d_in[0];
  const int*   mode = (const int*)d_in[1];
  const float* Wq   = (const float*)d_in[2];
  const float* bq   = (const float*)d_in[3];
  const float* Wk   = (const float*)d_in[4];
  const float* bk   = (const float*)d_in[5];
  const float* Wv   = (const float*)d_in[6];
  const float* bv   = (const float*)d_in[7];
  const float* Wa   = (const float*)d_in[8];
  const float* ba   = (const float*)d_in[9];
  const float* Ratt = (const float*)d_in[10];
  const float* Rmsg = (const float*)d_in[11];
  const float* post = (const float*)d_in[12];

  char* w = (char*)d_ws;
  u16* Wft   = (u16*)w;   w += SZ_WFT;
  float* bff = (float*)w; w += SZ_BFF;
  u16* Wqf   = (u16*)w;   w += SZ_WQF;
  u16* Waf   = (u16*)w;   w += SZ_WAF;
  u16* qbuf  = (u16*)w;   w += SZ_Q;
  u16* aout  = (u16*)w;   w += SZ_AOUT;
  u16* kwbuf = (u16*)w;   w += (size_t)nb*SZ_KW1;
  u16* vmbuf = (u16*)w;   w += (size_t)nb*SZ_VM1;

  fuse_all<<<1540, 512, 0, stream>>>(Wk, Wv, Ratt, Rmsg, Wq, Wa, bk, bv,
                                     Wft, bff, Wqf, Waf);
  gemm_qp<<<392, 256, 0, stream>>>(x, mode, Wqf, bq, qbuf);
  for (int b0 = 0; b0 < 4; b0 += nb) {
    gemm_kwv<<<nb*294, 512, 0, stream>>>(x, mode, Wft, bff, kwbuf, vmbuf, b0);
    attn_kernel<<<nb*512, 64, 0, stream>>>(qbuf, kwbuf, vmbuf, post, aout, b0);
  }
  gemm_op<<<392, 256, 0, stream>>>(aout, mode, Waf, ba, outp);
}

// Round 9
// 252.918 us; speedup vs baseline: 1.5817x; 1.0730x over previous
//
#include <hip/hip_runtime.h>

typedef unsigned short u16;
typedef unsigned int   u32;
typedef _Float16 f16;
typedef _Float16 h2  __attribute__((ext_vector_type(2)));
typedef _Float16 h8  __attribute__((ext_vector_type(8)));
typedef float    fx4 __attribute__((ext_vector_type(4)));

// ---- problem constants ----
// B=4 L=6 X=Y=8 -> 256 sites, W=49 window, D=256, h=8, dh=32
#define SCALE_Q 0.17677669529663687f

__device__ __forceinline__ u16 f2h_bits(float f){
  union{ f16 h; u16 u; } v; v.h = (f16)f; return v.u;
}
__device__ __forceinline__ u32 packh2(float a, float b){
  union{ h2 h; u32 u; } v; v.h = h2{(f16)a, (f16)b}; return v.u;
}
__device__ __forceinline__ h2 as_h2(u32 x){
  union{ u32 u; h2 h; } v; v.u = x; return v.h;
}
__device__ __forceinline__ h8 as_h8(uint4 u){
  union{ uint4 u; h8 h; } v; v.u = u; return v.h;
}

// diagnostic fill (fp32): encodes which runtime assumption failed
__global__ void flag_fill(float* out, int n, float v){
  int i = blockIdx.x*256 + threadIdx.x;
  if (i < n) out[i] = v;
}

// ---------------------------------------------------------------------------
// K0 (merged): fuse_w + fuse_b + fuse_qo in ONE launch.
// ---------------------------------------------------------------------------
__global__ __launch_bounds__(512) void fuse_all(
    const float* __restrict__ Wk, const float* __restrict__ Wv,
    const float* __restrict__ Ratt, const float* __restrict__ Rmsg,
    const float* __restrict__ Wq, const float* __restrict__ Wa,
    const float* __restrict__ bk, const float* __restrict__ bv,
    u16* __restrict__ Wft, float* __restrict__ bff,
    u16* __restrict__ Wqf, u16* __restrict__ Waf)
{
  const int blk = blockIdx.x;
  const int n = threadIdx.x;
  if (blk < 1024){
    const int rel = blk >> 8, d = blk & 255, ml = rel & 1;
    float acc = 0.f;
    if (n < 256) {
      const int h = n >> 5, p = n & 31;
      const float* wcol = Wk + (size_t)ml*65536 + (size_t)(h*32)*256 + d;
      const float* rrow = Ratt + ((size_t)(rel*8 + h)*32 + p)*32;
      #pragma unroll
      for (int q = 0; q < 32; ++q) acc += wcol[q*256] * rrow[q];
    } else {
      const int n2 = n - 256, h = n2 >> 5, qq = n2 & 31;
      const float* wcol = Wv + (size_t)ml*65536 + (size_t)(h*32)*256 + d;
      const float* rcol = Rmsg + ((size_t)(rel*8 + h)*32)*32 + qq;
      #pragma unroll
      for (int p2 = 0; p2 < 32; ++p2) acc += wcol[p2*256] * rcol[p2*32];
    }
    Wft[(size_t)rel*131072 + (size_t)(d >> 5)*16384 + (size_t)n*32 + (d & 31)] = f2h_bits(acc);
  } else if (blk < 1028){
    const int rel = blk - 1024, ml = rel & 1;
    float acc = 0.f;
    if (n < 256) {
      const int h = n >> 5, p = n & 31;
      const float* rrow = Ratt + ((size_t)(rel*8 + h)*32 + p)*32;
      #pragma unroll
      for (int q = 0; q < 32; ++q) acc += bk[ml*256 + h*32 + q] * rrow[q];
    } else {
      const int n2 = n - 256, h = n2 >> 5, qq = n2 & 31;
      const float* rcol = Rmsg + ((size_t)(rel*8 + h)*32)*32 + qq;
      #pragma unroll
      for (int p2 = 0; p2 < 32; ++p2) acc += bv[ml*256 + h*32 + p2] * rcol[p2*32];
    }
    bff[rel*512 + n] = acc;
  } else {
    const int bb = blk - 1028;
    const int t = bb >> 8, d = bb & 255;
    if (n < 256){
      float v = Wq[(size_t)t*65536 + (size_t)n*256 + d] * SCALE_Q;
      Wqf[(size_t)t*65536 + (size_t)(d >> 5)*8192 + (size_t)n*32 + (d & 31)] = f2h_bits(v);
    } else {
      const int e = n - 256;
      float v = Wa[(size_t)t*65536 + (size_t)e*256 + d];
      Waf[(size_t)t*65536 + (size_t)(d >> 5)*8192 + (size_t)e*32 + (d & 31)] = f2h_bits(v);
    }
  }
}

// ---------------------------------------------------------------------------
// K1 v7b: fused kw / v_msg projection GEMM — MFMA (16x16x32 f16). (unchanged)
// ---------------------------------------------------------------------------
#define ASTRIDE 264   // u16 elements per LDS row (16B-aligned, conflict-light)

__global__ __launch_bounds__(512) void gemm_kwv(
    const float* __restrict__ x, const int* __restrict__ mode,
    const u16* __restrict__ Wft, const float* __restrict__ bff,
    u16* __restrict__ kw, u16* __restrict__ vm, int b0)
{
  __shared__ u16 Smem[64*ASTRIDE];   // 33.8 KB: A-tile, then epilogue buffer
  const int rowT  = blockIdx.x;              // bloc*294 + l*49 + tile
  const int bloc = rowT / 294;
  const int rem  = rowT % 294;
  const int l = rem / 49, tile = rem % 49;
  const int b = b0 + bloc;
  const int rel = mode[b*6]*2 + mode[b*6 + l];
  const float* Abase = x + ((size_t)(b*6 + l)*3136 + (size_t)tile*64)*256;
  const int tid  = threadIdx.x;
  const int wave = tid >> 6, lane = tid & 63;
  const int quad = lane >> 4, l15 = lane & 15;

  const u16* Bp = Wft + (size_t)rel*131072 + (size_t)((wave << 6) + l15)*32 + (quad << 3);

  uint4 breg[3][4];
  #pragma unroll
  for (int s = 0; s < 3; ++s)
    #pragma unroll
    for (int j = 0; j < 4; ++j){
      const u16* ap = Bp + (size_t)s*16384 + j*512;
      asm volatile("global_load_dwordx4 %0, %1, off" : "=v"(breg[s][j]) : "v"(ap));
    }

  #pragma unroll
  for (int i = 0; i < 8; ++i){
    float4 f = *(const float4*)(Abase + (size_t)i*2048 + tid*4);
    const int row = i*8 + (tid >> 6), col = (tid & 63)*4;
    uint2 pk; pk.x = packh2(f.x, f.y); pk.y = packh2(f.z, f.w);
    *(uint2*)&Smem[row*ASTRIDE + col] = pk;
  }
  __syncthreads();   // compiler drains vmcnt before s_barrier: slots 0..2 ready

  fx4 acc[4][4];
  #pragma unroll
  for (int mt = 0; mt < 4; ++mt)
    #pragma unroll
    for (int j = 0; j < 4; ++j) acc[mt][j] = fx4{0,0,0,0};

  const u16* As = &Smem[l15*ASTRIDE + (quad << 3)];

  #pragma unroll
  for (int s = 0; s < 8; ++s){
    if (s >= 3 && s <= 5)      { asm volatile("s_waitcnt vmcnt(8)" ::: "memory"); }
    else if (s == 6)           { asm volatile("s_waitcnt vmcnt(4)" ::: "memory"); }
    else if (s == 7)           { asm volatile("s_waitcnt vmcnt(0)" ::: "memory"); }
    __builtin_amdgcn_sched_barrier(0);
    h8 af[4];
    #pragma unroll
    for (int mt = 0; mt < 4; ++mt)
      af[mt] = *(const h8*)(As + (mt*16)*ASTRIDE + s*32);
    const int slot = s % 3;
    #pragma unroll
    for (int j = 0; j < 4; ++j){
      h8 bf = as_h8(breg[slot][j]);
      #pragma unroll
      for (int mt = 0; mt < 4; ++mt)
        acc[mt][j] = __builtin_amdgcn_mfma_f32_16x16x32_f16(af[mt], bf, acc[mt][j], 0, 0, 0);
    }
    if (s < 5){
      #pragma unroll
      for (int j = 0; j < 4; ++j){
        const u16* ap = Bp + (size_t)(s + 3)*16384 + j*512;
        asm volatile("global_load_dwordx4 %0, %1, off" : "=v"(breg[slot][j]) : "v"(ap));
      }
    }
  }

  const int row_ = tid >> 3;        // 0..63
  const int hsel = tid & 7;         // 0..7
  const int r_g  = tile*64 + row_;  // 0..3135
  const int xy   = r_g / 49, ef = r_g - xy*49;

  #pragma unroll
  for (int half = 0; half < 2; ++half){
    __syncthreads();
    if ((wave >> 2) == half){
      #pragma unroll
      for (int j = 0; j < 4; ++j){
        const int n   = wave*64 + j*16 + l15;   // 0..511
        const int col = n & 255;
        const float bias = bff[rel*512 + n];
        #pragma unroll
        for (int mt = 0; mt < 4; ++mt){
          #pragma unroll
          for (int reg = 0; reg < 4; ++reg){
            const int row = mt*16 + quad*4 + reg;
            Smem[row*ASTRIDE + col] = f2h_bits(acc[mt][j][reg] + bias);
          }
        }
      }
    }
    __syncthreads();
    u16* dbuf = half ? vm : kw;
    u16* dst  = dbuf + ((((size_t)(bloc*64 + xy)*8 + hsel)*6 + l)*49 + ef)*32;
    const u16* srcl = &Smem[row_*ASTRIDE + hsel*32];
    *(uint4*)(dst)      = *(const uint4*)(srcl);
    *(uint4*)(dst + 8)  = *(const uint4*)(srcl + 8);
    *(uint4*)(dst + 16) = *(const uint4*)(srcl + 16);
    *(uint4*)(dst + 24) = *(const uint4*)(srcl + 24);
  }
}

// ---------------------------------------------------------------------------
// K2 v2: q projection (l=0 only) — MFMA. BM=32, BN=256, grid = 4*98. (unchanged)
// ---------------------------------------------------------------------------
__global__ __launch_bounds__(256, 2) void gemm_qp(
    const float* __restrict__ x, const int* __restrict__ mode,
    const u16* __restrict__ Wqf, const float* __restrict__ bq,
    u16* __restrict__ qbuf)
{
  __shared__ u16 Smem[32*ASTRIDE];
  const int rowT = blockIdx.x;       // b*98 + tile
  const int b = rowT / 98, tile = rowT % 98;
  const int m0 = mode[b*6];
  const float* Abase = x + ((size_t)(b*6)*3136 + (size_t)tile*32)*256;
  const int tid = threadIdx.x;
  const int wave = tid >> 6, lane = tid & 63;
  const int quad = lane >> 4, l15 = lane & 15;

  const u16* Bp = Wqf + (size_t)m0*65536 + (size_t)((wave << 6) + l15)*32 + (quad << 3);
  uint4 breg[32];
  #pragma unroll
  for (int s = 0; s < 8; ++s)
    #pragma unroll
    for (int j = 0; j < 4; ++j){
      const u16* ap = Bp + (size_t)s*8192 + j*512;
      asm volatile("global_load_dwordx4 %0, %1, off" : "=v"(breg[s*4+j]) : "v"(ap));
    }

  {
    const int r = tid >> 3, cseg = (tid & 7)*32;
    const float* src = Abase + (size_t)r*256 + cseg;
    u16* dst = &Smem[r*ASTRIDE + cseg];
    #pragma unroll
    for (int i = 0; i < 4; ++i){
      float4 f0 = *(const float4*)(src + i*8);
      float4 f1 = *(const float4*)(src + i*8 + 4);
      uint4 pk;
      pk.x = packh2(f0.x, f0.y); pk.y = packh2(f0.z, f0.w);
      pk.z = packh2(f1.x, f1.y); pk.w = packh2(f1.z, f1.w);
      *(uint4*)(dst + i*8) = pk;
    }
  }
  __syncthreads();

  fx4 acc[2][4];
  #pragma unroll
  for (int mt = 0; mt < 2; ++mt)
    #pragma unroll
    for (int j = 0; j < 4; ++j) acc[mt][j] = fx4{0,0,0,0};

  const u16* As0 = &Smem[l15*ASTRIDE + (quad << 3)];
  const u16* As1 = As0 + 16*ASTRIDE;
  asm volatile("s_waitcnt vmcnt(0)" ::: "memory");
  __builtin_amdgcn_sched_barrier(0);
  #pragma unroll
  for (int s = 0; s < 8; ++s){
    h8 af0 = *(const h8*)(As0 + s*32);
    h8 af1 = *(const h8*)(As1 + s*32);
    #pragma unroll
    for (int j = 0; j < 4; ++j){
      h8 bf = as_h8(breg[s*4+j]);
      acc[0][j] = __builtin_amdgcn_mfma_f32_16x16x32_f16(af0, bf, acc[0][j], 0, 0, 0);
      acc[1][j] = __builtin_amdgcn_mfma_f32_16x16x32_f16(af1, bf, acc[1][j], 0, 0, 0);
    }
  }

  __syncthreads();
  #pragma unroll
  for (int j = 0; j < 4; ++j){
    const int n = wave*64 + j*16 + l15;
    const float bias = bq[m0*256 + n] * SCALE_Q;
    #pragma unroll
    for (int mt = 0; mt < 2; ++mt)
      #pragma unroll
      for (int reg = 0; reg < 4; ++reg){
        const int row = mt*16 + quad*4 + reg;
        Smem[row*ASTRIDE + n] = f2h_bits(acc[mt][j][reg] + bias);
      }
  }
  __syncthreads();
  {
    const int row_ = tid >> 3, hsel = tid & 7;
    const int r_g = tile*32 + row_;
    const int xy = r_g / 49, ef = r_g - xy*49;
    u16* dst = qbuf + (((size_t)(b*64 + xy)*8 + hsel)*49 + ef)*32;
    const u16* srcl = &Smem[row_*ASTRIDE + hsel*32];
    *(uint4*)(dst)      = *(const uint4*)(srcl);
    *(uint4*)(dst + 8)  = *(const uint4*)(srcl + 8);
    *(uint4*)(dst + 16) = *(const uint4*)(srcl + 16);
    *(uint4*)(dst + 24) = *(const uint4*)(srcl + 24);
  }
}

// ---------------------------------------------------------------------------
// K3 v8: attention — ONE WAVE per (bloc,xy,h), MFMA, LDS DOUBLE-BUFFER
// pipeline, ALL-C++ staging (no asm in the data path).
// v7/v7b (asm-pinned register prefetch) failed correctness twice with an
// unconfirmed mechanism (suspect: allocator spill/move of asm-written regs
// between load issue and vmcnt wait). v8 removes the entire asm class:
// Ks/VT are 2x buffers; z+1 is loaded into plain C++ locals at loop top
// (scheduler hoists the global loads; uses are ~200 insts later), compute
// runs on buf[cur], then C++ stores stage buf[cur^1]. Compiler inserts all
// waits -> correct by construction; WAR-free (different buffers).
// ---------------------------------------------------------------------------
#define LGKM0  do{ asm volatile("s_waitcnt lgkmcnt(0)" ::: "memory"); \
                   __builtin_amdgcn_sched_barrier(0); }while(0)

__device__ __forceinline__ void scatter_v(u16* VTb, int i4, uint4 vv){
  const int ef = i4 >> 2, pb = (i4 & 3)*8, c0 = ef >> 3;
  u16* vt = VTb + (ef & 7);
  vt[(pb+0)*64 + ((c0 ^ 0) << 3)] = (u16)(vv.x & 0xFFFFu);
  vt[(pb+1)*64 + ((c0 ^ 1) << 3)] = (u16)(vv.x >> 16);
  vt[(pb+2)*64 + ((c0 ^ 2) << 3)] = (u16)(vv.y & 0xFFFFu);
  vt[(pb+3)*64 + ((c0 ^ 3) << 3)] = (u16)(vv.y >> 16);
  vt[(pb+4)*64 + ((c0 ^ 4) << 3)] = (u16)(vv.z & 0xFFFFu);
  vt[(pb+5)*64 + ((c0 ^ 5) << 3)] = (u16)(vv.z >> 16);
  vt[(pb+6)*64 + ((c0 ^ 6) << 3)] = (u16)(vv.w & 0xFFFFu);
  vt[(pb+7)*64 + ((c0 ^ 7) << 3)] = (u16)(vv.w >> 16);
}

__global__ __launch_bounds__(64) void attn_kernel(
    const u16* __restrict__ qbuf, const u16* __restrict__ kw,
    const u16* __restrict__ vm,   const float* __restrict__ post,
    u16* __restrict__ aout, int b0)
{
  __shared__ u32 Ks[2*64*16];   // 2 buffers: K rows [ke][p], pad rows zero  8KB
  __shared__ u16 VT[2*32*64];   // 2 buffers: V^T [p][ke] chunk-XOR-swizzled 8KB
  __shared__ u16 PQ[64*64];     // Q staging [qi][32] -> P^T [qi][ke] swz    8KB
  __shared__ float poss[169];

  const int bloc  = blockIdx.x >> 9;
  const int local = blockIdx.x & 511;      // xy*8+h
  const int h = local & 7, xy = local >> 3;
  const int bxy = (b0 + bloc)*64 + xy;
  const int lane = threadIdx.x;            // 0..63
  const int quad = lane >> 4, l15 = lane & 15;

  const size_t kvbase = ((size_t)(bloc*64 + xy)*8 + h)*6;

  for (int i = lane; i < 169; i += 64) poss[i] = post[i*8 + h];
  for (int i = lane; i < 480; i += 64){                     // K pad rows, both bufs
    const int bb = i / 240, o = i - bb*240;
    Ks[bb*1024 + 784 + o] = 0;
  }
  for (int i = lane; i < 1024; i += 64){                    // VT pad ke 48..63, both bufs
    const int bb = i >> 9, r = i & 511;
    const int p = r >> 4, ke = 48 + (r & 15);
    VT[bb*2048 + p*64 + ((((ke >> 3) ^ (p & 7)) & 7) << 3) + (ke & 7)] = 0;
  }
  { const u16* qsrc = qbuf + (size_t)(bxy*8 + h)*1568;      // Q rows -> PQ[qi][32]
    for (int i = lane; i < 196; i += 64)
      *(uint4*)&PQ[(i >> 2)*32 + (i & 3)*8] = *(const uint4*)(qsrc + (size_t)i*8);
    const uint4 z4 = make_uint4(0,0,0,0);
    for (int i = lane; i < 60; i += 64)                     // rows 49..63 zero
      *(uint4*)&PQ[1568 + i*8] = z4;
  }
  // ---- stage z=0 into buffer 0 (plain C++, v6-style) ----
  { const uint4* ksrc = (const uint4*)((const u32*)kw + kvbase*784);
    for (int i = lane; i < 196; i += 64) ((uint4*)Ks)[i] = ksrc[i];
    const uint4* vsrc = (const uint4*)((const u32*)vm + kvbase*784);
    for (int i = lane; i < 196; i += 64) scatter_v(VT, i, vsrc[i]);
  }
  LGKM0;   // single-wave block: lgkmcnt(0) replaces __syncthreads

  // Q B-frags (persist across all z)
  h8 qf[4];
  #pragma unroll
  for (int nt = 0; nt < 4; ++nt)
    qf[nt] = *(const h8*)&PQ[(nt*16 + l15)*32 + quad*8];

  // bias C-in frags (persist): element (ke = mt*16+quad*4+reg, qi = nt*16+l15)
  fx4 bias[4][4];
  { int qa[4], qb[4];
    #pragma unroll
    for (int nt = 0; nt < 4; ++nt){
      const int qi = nt*16 + l15; qa[nt] = qi/7; qb[nt] = qi - qa[nt]*7;
    }
    #pragma unroll
    for (int mt = 0; mt < 4; ++mt)
      #pragma unroll
      for (int reg = 0; reg < 4; ++reg){
        const int ke = mt*16 + quad*4 + reg;
        const int ka = ke/7, kb = ke - ka*7;
        #pragma unroll
        for (int nt = 0; nt < 4; ++nt){
          const int qi = nt*16 + l15;
          float bv;
          if (ke > 48)      bv = -1e30f;
          else if (qi > 48) bv = 0.f;
          else              bv = poss[(qa[nt] - ka + 6)*13 + (qb[nt] - kb + 6)];
          bias[mt][nt][reg] = bv;
        }
      }
  }

  float mprev[4], lsum[4];
  fx4 Oacc[2][4];
  #pragma unroll
  for (int nt = 0; nt < 4; ++nt){
    mprev[nt] = -1e30f; lsum[nt] = 0.f;
    Oacc[0][nt] = fx4{0,0,0,0}; Oacc[1][nt] = fx4{0,0,0,0};
  }

  int cur = 0;
  for (int z = 0; z < 6; ++z){
    // ---- prefetch z+1 into C++ locals (scheduler hoists; no asm) ----
    uint4 kn0, kn1, kn2, kn3, vn0, vn1, vn2, vn3;
    if (z < 5){
      const uint4* ksrc = (const uint4*)((const u32*)kw + (kvbase + z + 1)*784);
      const uint4* vsrc = (const uint4*)((const u32*)vm + (kvbase + z + 1)*784);
      kn0 = ksrc[lane]; kn1 = ksrc[64 + lane]; kn2 = ksrc[128 + lane];
      vn0 = vsrc[lane]; vn1 = vsrc[64 + lane]; vn2 = vsrc[128 + lane];
      if (lane < 4){ kn3 = ksrc[192 + lane]; vn3 = vsrc[192 + lane]; }
    }

    const u32* KsC = Ks + cur*1024;
    const u16* VTC = VT + cur*2048;

    // ---- S^T = K·Q^T + bias (16 MFMA) ----
    h8 kf[4];
    #pragma unroll
    for (int mt = 0; mt < 4; ++mt)
      kf[mt] = *(const h8*)((const u16*)KsC + (mt*16 + l15)*32 + quad*8);
    fx4 S[4][4];
    #pragma unroll
    for (int mt = 0; mt < 4; ++mt)
      #pragma unroll
      for (int nt = 0; nt < 4; ++nt)
        S[mt][nt] = __builtin_amdgcn_mfma_f32_16x16x32_f16(kf[mt], qf[nt], bias[mt][nt], 0, 0, 0);

    // ---- online softmax per qi-column group nt ----
    #pragma unroll
    for (int nt = 0; nt < 4; ++nt){
      float cm = S[0][nt][0];
      #pragma unroll
      for (int mt = 0; mt < 4; ++mt)
        #pragma unroll
        for (int r = 0; r < 4; ++r) cm = fmaxf(cm, S[mt][nt][r]);
      cm = fmaxf(cm, __shfl_xor(cm, 16));
      cm = fmaxf(cm, __shfl_xor(cm, 32));
      const float mnew = fmaxf(mprev[nt], cm);
      const float alpha = __expf(mprev[nt] - mnew);
      mprev[nt] = mnew;
      float sum = 0.f;
      #pragma unroll
      for (int mt = 0; mt < 4; ++mt)
        #pragma unroll
        for (int r = 0; r < 4; ++r){
          float e = __expf(S[mt][nt][r] - mnew); S[mt][nt][r] = e; sum += e;
        }
      sum += __shfl_xor(sum, 16);
      sum += __shfl_xor(sum, 32);
      lsum[nt] = lsum[nt]*alpha + sum;
      #pragma unroll
      for (int r = 0; r < 4; ++r){ Oacc[0][nt][r] *= alpha; Oacc[1][nt][r] *= alpha; }
    }

    // ---- pack P^T into PQ (swizzled): ke chunk = mt*2 + (quad>>1) ----
    #pragma unroll
    for (int nt = 0; nt < 4; ++nt){
      const int qi = nt*16 + l15;
      u16* prow = &PQ[qi*64 + ((quad & 1) << 2)];
      #pragma unroll
      for (int mt = 0; mt < 4; ++mt){
        const int chk = (mt*2 + (quad >> 1)) ^ (l15 & 7);
        uint2 w;
        w.x = packh2(S[mt][nt][0], S[mt][nt][1]);
        w.y = packh2(S[mt][nt][2], S[mt][nt][3]);
        *(uint2*)(prow + (chk << 3)) = w;
      }
    }
    LGKM0;   // P^T visible

    // ---- O^T += V^T · P^T (16 MFMA over 2 k-steps) ----
    #pragma unroll
    for (int ks = 0; ks < 2; ++ks){
      h8 vf[2];
      #pragma unroll
      for (int m2 = 0; m2 < 2; ++m2)
        vf[m2] = *(const h8*)&VTC[(m2*16 + l15)*64 + (((ks*4 + quad) ^ (l15 & 7)) << 3)];
      #pragma unroll
      for (int nt = 0; nt < 4; ++nt){
        h8 pf = *(const h8*)&PQ[(nt*16 + l15)*64 + (((ks*4 + quad) ^ (l15 & 7)) << 3)];
        Oacc[0][nt] = __builtin_amdgcn_mfma_f32_16x16x32_f16(vf[0], pf, Oacc[0][nt], 0, 0, 0);
        Oacc[1][nt] = __builtin_amdgcn_mfma_f32_16x16x32_f16(vf[1], pf, Oacc[1][nt], 0, 0, 0);
      }
    }

    // ---- stage z+1 into the OTHER buffer (WAR-free by construction) ----
    if (z < 5){
      u32* KsN = Ks + (cur ^ 1)*1024;
      u16* VTN = VT + (cur ^ 1)*2048;
      ((uint4*)KsN)[lane]       = kn0;
      ((uint4*)KsN)[64 + lane]  = kn1;
      ((uint4*)KsN)[128 + lane] = kn2;
      scatter_v(VTN, lane,       vn0);
      scatter_v(VTN, 64 + lane,  vn1);
      scatter_v(VTN, 128 + lane, vn2);
      if (lane < 4){
        ((uint4*)KsN)[192 + lane] = kn3;
        scatter_v(VTN, 192 + lane, vn3);
      }
    }
    LGKM0;   // staging visible before next iteration reads it
    cur ^= 1;
  }

  // ---- normalize + store via LDS roundtrip ----
  #pragma unroll
  for (int nt = 0; nt < 4; ++nt){
    const int qi = nt*16 + l15;
    if (qi < 49){
      const float inv = 1.f / lsum[nt];
      #pragma unroll
      for (int m2 = 0; m2 < 2; ++m2){
        uint2 w;
        w.x = packh2(Oacc[m2][nt][0]*inv, Oacc[m2][nt][1]*inv);
        w.y = packh2(Oacc[m2][nt][2]*inv, Oacc[m2][nt][3]*inv);
        *(uint2*)&PQ[qi*32 + m2*16 + quad*4] = w;
      }
    }
  }
  LGKM0;
  { u16* obase = aout + (size_t)bxy*12544 + h*32;
    for (int i = lane; i < 196; i += 64){
      const int r = i >> 2, c = (i & 3)*8;
      *(uint4*)(obase + (size_t)r*256 + c) = *(const uint4*)&PQ[r*32 + c];
    }
  }
}

// ---------------------------------------------------------------------------
// K4 v2: final projection — MFMA. A = aout f16, B = Waf[m0] k-step-major,
// bias ba, fp32 out via LDS float transpose. BM=32, BN=256, grid = 4*98.
// ---------------------------------------------------------------------------
__global__ __launch_bounds__(256, 2) void gemm_op(
    const u16* __restrict__ aout, const int* __restrict__ mode,
    const u16* __restrict__ Waf, const float* __restrict__ ba,
    float* __restrict__ outp)
{
  __shared__ float Smf[32*260];          // 33.3 KB; low half doubles as u16 A-tile
  u16* Smem = (u16*)Smf;
  const int rowT = blockIdx.x;       // b*98 + tile
  const int b = rowT / 98, tile = rowT % 98;
  const int m0 = mode[b*6];
  const u16* Abase = aout + ((size_t)b*3136 + (size_t)tile*32)*256;
  const int tid = threadIdx.x;
  const int wave = tid >> 6, lane = tid & 63;
  const int quad = lane >> 4, l15 = lane & 15;

  const u16* Bp = Waf + (size_t)m0*65536 + (size_t)((wave << 6) + l15)*32 + (quad << 3);
  uint4 breg[32];
  #pragma unroll
  for (int s = 0; s < 8; ++s)
    #pragma unroll
    for (int j = 0; j < 4; ++j){
      const u16* ap = Bp + (size_t)s*8192 + j*512;
      asm volatile("global_load_dwordx4 %0, %1, off" : "=v"(breg[s*4+j]) : "v"(ap));
    }

  {
    const int r = tid >> 3, cseg = (tid & 7)*32;
    const u16* src = Abase + (size_t)r*256 + cseg;
    u16* dst = &Smem[r*ASTRIDE + cseg];
    #pragma unroll
    for (int i = 0; i < 4; ++i)
      *(uint4*)(dst + i*8) = *(const uint4*)(src + i*8);
  }
  __syncthreads();

  fx4 acc[2][4];
  #pragma unroll
  for (int mt = 0; mt < 2; ++mt)
    #pragma unroll
    for (int j = 0; j < 4; ++j) acc[mt][j] = fx4{0,0,0,0};

  const u16* As0 = &Smem[l15*ASTRIDE + (quad << 3)];
  const u16* As1 = As0 + 16*ASTRIDE;
  asm volatile("s_waitcnt vmcnt(0)" ::: "memory");
  __builtin_amdgcn_sched_barrier(0);
  #pragma unroll
  for (int s = 0; s < 8; ++s){
    h8 af0 = *(const h8*)(As0 + s*32);
    h8 af1 = *(const h8*)(As1 + s*32);
    #pragma unroll
    for (int j = 0; j < 4; ++j){
      h8 bf = as_h8(breg[s*4+j]);
      acc[0][j] = __builtin_amdgcn_mfma_f32_16x16x32_f16(af0, bf, acc[0][j], 0, 0, 0);
      acc[1][j] = __builtin_amdgcn_mfma_f32_16x16x32_f16(af1, bf, acc[1][j], 0, 0, 0);
    }
  }

  __syncthreads();
  #pragma unroll
  for (int j = 0; j < 4; ++j){
    const int n = wave*64 + j*16 + l15;
    const float bias = ba[m0*256 + n];
    #pragma unroll
    for (int mt = 0; mt < 2; ++mt)
      #pragma unroll
      for (int reg = 0; reg < 4; ++reg){
        const int row = mt*16 + quad*4 + reg;
        Smf[row*260 + n] = acc[mt][j][reg] + bias;
      }
  }
  __syncthreads();
  {
    const int row_ = tid >> 3, seg = (tid & 7)*32;
    const int rowg = b*3136 + tile*32 + row_;
    float* dst = outp + (size_t)rowg*256 + seg;
    const float* srcl = &Smf[row_*260 + seg];
    #pragma unroll
    for (int i = 0; i < 8; ++i)
      *(float4*)(dst + i*4) = *(const float4*)(srcl + i*4);
  }
}

// ---------------------------------------------------------------------------
extern "C" void kernel_launch(void* const* d_in, const int* in_sizes, int n_in,
                              void* d_out, int out_size, void* d_ws, size_t ws_size,
                              hipStream_t stream)
{
  float* outp = (float*)d_out;
  const int FLAG_GRID = (out_size + 255)/256;

  if (n_in != 13) { flag_fill<<<FLAG_GRID,256,0,stream>>>(outp, out_size, 2000.f); return; }
  if (in_sizes[0] != 4*6*64*49*256) { flag_fill<<<FLAG_GRID,256,0,stream>>>(outp, out_size, 3000.f); return; }
  if (in_sizes[1] != 24) { flag_fill<<<FLAG_GRID,256,0,stream>>>(outp, out_size, 4000.f); return; }

  const size_t SZ_WFT  = (size_t)4*512*256*2;               //  1 MB (f16)
  const size_t SZ_BFF  = (size_t)4*512*sizeof(float);       //  8 KB
  const size_t SZ_WQF  = (size_t)2*256*256*2;               //  256 KB (f16)
  const size_t SZ_WAF  = (size_t)2*256*256*2;               //  256 KB (f16)
  const size_t SZ_Q    = (size_t)12544*256*2;               //  6.4 MB (f16)
  const size_t SZ_AOUT = (size_t)12544*256*2;               //  6.4 MB (f16)
  const size_t SZ_KW1  = (size_t)64*8*6*49*32*2;            //  9.63 MB / batch
  const size_t SZ_VM1  = SZ_KW1;                            //  unified layout
  const size_t FIXED   = SZ_WFT + SZ_BFF + SZ_WQF + SZ_WAF + SZ_Q + SZ_AOUT;
  if (ws_size < FIXED + SZ_KW1 + SZ_VM1) { flag_fill<<<FLAG_GRID,256,0,stream>>>(outp, out_size, 1000.f); return; }

  int nb = 1;
  if (ws_size >= FIXED + 4*(SZ_KW1 + SZ_VM1)) nb = 4;
  else if (ws_size >= FIXED + 2*(SZ_KW1 + SZ_VM1)) nb = 2;

  const float* x    = (const float*)d_in[0];
  const int*   mode = (const int*)d_in[1];
  const float* Wq   = (const float*)d_in[2];
  const float* bq   = (const float*)d_in[3];
  const float* Wk   = (const float*)d_in[4];
  const float* bk   = (const float*)d_in[5];
  const float* Wv   = (const float*)d_in[6];
  const float* bv   = (const float*)d_in[7];
  const float* Wa   = (const float*)d_in[8];
  const float* ba   = (const float*)d_in[9];
  const float* Ratt = (const float*)d_in[10];
  const float* Rmsg = (const float*)d_in[11];
  const float* post = (const float*)d_in[12];

  char* w = (char*)d_ws;
  u16* Wft   = (u16*)w;   w += SZ_WFT;
  float* bff = (float*)w; w += SZ_BFF;
  u16* Wqf   = (u16*)w;   w += SZ_WQF;
  u16* Waf   = (u16*)w;   w += SZ_WAF;
  u16* qbuf  = (u16*)w;   w += SZ_Q;
  u16* aout  = (u16*)w;   w += SZ_AOUT;
  u16* kwbuf = (u16*)w;   w += (size_t)nb*SZ_KW1;
  u16* vmbuf = (u16*)w;   w += (size_t)nb*SZ_VM1;

  fuse_all<<<1540, 512, 0, stream>>>(Wk, Wv, Ratt, Rmsg, Wq, Wa, bk, bv,
                                     Wft, bff, Wqf, Waf);
  gemm_qp<<<392, 256, 0, stream>>>(x, mode, Wqf, bq, qbuf);
  for (int b0 = 0; b0 < 4; b0 += nb) {
    gemm_kwv<<<nb*294, 512, 0, stream>>>(x, mode, Wft, bff, kwbuf, vmbuf, b0);
    attn_kernel<<<nb*512, 64, 0, stream>>>(qbuf, kwbuf, vmbuf, post, aout, b0);
  }
  gemm_op<<<392, 256, 0, stream>>>(aout, mode, Waf, ba, outp);
}